// Round 1
// baseline (591.167 us; speedup 1.0000x reference)
//
#include <hip/hip_runtime.h>

// ---------------------------------------------------------------------------
// QGCN forward: 3 GCN layers.
//   L1: h1 = x@W1 ; x1 = agg(h1)+b1 ; h = x1 + relu(x1)
//   L2: h2 = h@W2 ; t  = agg(h2)+b2 ; h = x1 + relu(t)
//   L3: h3 = h@W3 ; out= agg(h3)+b3
// agg is edge-weighted scatter-add by dst; implemented as CSR-gather (built
// on device each call: histogram -> scan -> fill) to avoid 256M fp32 atomics.
// ---------------------------------------------------------------------------

__device__ __forceinline__ float relu_f(float v) { return v > 0.f ? v : 0.f; }

__global__ __launch_bounds__(256) void count_kernel(const int* __restrict__ dst,
                                                    int* __restrict__ deg, int E) {
  int e = blockIdx.x * 256 + threadIdx.x;
  if (e < E) atomicAdd(&deg[dst[e]], 1);
}

// Single-block exclusive scan over n ints (Hillis-Steele per 1024-tile).
__global__ __launch_bounds__(1024) void scan_kernel(const int* __restrict__ deg,
                                                    int* __restrict__ offs,
                                                    int* __restrict__ cur, int n) {
  __shared__ int buf[1024];
  __shared__ int carry_s;
  const int t = threadIdx.x;
  if (t == 0) carry_s = 0;
  __syncthreads();
  for (int base = 0; base < n; base += 1024) {
    int i = base + t;
    int v = (i < n) ? deg[i] : 0;
    buf[t] = v;
    __syncthreads();
    for (int off = 1; off < 1024; off <<= 1) {
      int y = (t >= off) ? buf[t - off] : 0;
      __syncthreads();
      buf[t] += y;
      __syncthreads();
    }
    int incl = buf[t];
    int carry = carry_s;
    if (i < n) {
      int ex = carry + incl - v;
      offs[i] = ex;
      cur[i] = ex;
    }
    __syncthreads();
    if (t == 1023) carry_s = carry + incl;
    __syncthreads();
  }
  if (t == 0) offs[n] = carry_s;
}

__global__ __launch_bounds__(256) void fill_kernel(const int* __restrict__ src,
                                                   const int* __restrict__ dst,
                                                   const float* __restrict__ ew,
                                                   int* __restrict__ cur,
                                                   int* __restrict__ es,
                                                   float* __restrict__ ewr, int E) {
  int e = blockIdx.x * 256 + threadIdx.x;
  if (e < E) {
    int d = dst[e];
    int pos = atomicAdd(&cur[d], 1);
    es[pos] = src[e];
    ewr[pos] = ew[e];
  }
}

// C[N,DOUT] = A[N,128] @ W[128,DOUT].  Block = 64 rows x DOUT cols,
// 256 threads, thread tile 4 rows x (DOUT/16) cols, K staged in 32-chunks.
template <int DOUT>
__global__ __launch_bounds__(256) void mm_kernel(const float* __restrict__ A,
                                                 const float* __restrict__ W,
                                                 float* __restrict__ C, int N) {
  constexpr int K = 128;
  constexpr int KT = 32;
  constexpr int TC = DOUT / 16;        // 8 (DOUT=128) or 4 (DOUT=64)
  constexpr int ASTRIDE = KT + 4;      // pad keeps 16B alignment, 2-way bank alias (free)
  __shared__ float Ws[KT * DOUT];
  __shared__ float As[64 * ASTRIDE];
  const int t = threadIdx.x;
  const int tx = t & 15;
  const int ty = t >> 4;
  const int row0 = blockIdx.x * 64;

  float acc[4][TC];
#pragma unroll
  for (int r = 0; r < 4; ++r)
#pragma unroll
    for (int c = 0; c < TC; ++c) acc[r][c] = 0.f;

  for (int k0 = 0; k0 < K; k0 += KT) {
    __syncthreads();
    {  // stage A tile: 64 x 32 floats, 8 per thread
      int r = t >> 2;
      int c = (t & 3) * 8;
      int row = row0 + r;
      if (row >= N) row = N - 1;  // clamp; garbage rows masked at store
      const float* s = &A[(size_t)row * K + k0 + c];
      float4 v0 = *(const float4*)s;
      float4 v1 = *(const float4*)(s + 4);
      float* d = &As[r * ASTRIDE + c];
      *(float4*)d = v0;
      *(float4*)(d + 4) = v1;
    }
#pragma unroll
    for (int i = t * 4; i < KT * DOUT; i += 1024) {  // stage W chunk
      *(float4*)&Ws[i] = *(const float4*)&W[k0 * DOUT + i];
    }
    __syncthreads();
#pragma unroll
    for (int kk = 0; kk < KT; ++kk) {
      float a[4];
#pragma unroll
      for (int r = 0; r < 4; ++r) a[r] = As[(ty * 4 + r) * ASTRIDE + kk];
      float w[TC];
#pragma unroll
      for (int c = 0; c < TC; c += 4)
        *(float4*)&w[c] = *(const float4*)&Ws[kk * DOUT + tx * TC + c];
#pragma unroll
      for (int r = 0; r < 4; ++r)
#pragma unroll
        for (int c = 0; c < TC; ++c) acc[r][c] = fmaf(a[r], w[c], acc[r][c]);
    }
  }
#pragma unroll
  for (int r = 0; r < 4; ++r) {
    int row = row0 + ty * 4 + r;
    if (row < N) {
#pragma unroll
      for (int c = 0; c < TC; c += 4) {
        float4 v;
        v.x = acc[r][c + 0]; v.y = acc[r][c + 1];
        v.z = acc[r][c + 2]; v.w = acc[r][c + 3];
        *(float4*)&C[(size_t)row * DOUT + tx * TC + c] = v;
      }
    }
  }
}

// Gather aggregation: one wave per dst node; lanes split the feature dim.
// MODE 0: x1 = acc+b  -> out_x1 = x1, out_main = x1 + relu(x1)
// MODE 1: t  = acc+b  -> out_main = x1in + relu(t)
// MODE 2 (D=64): out_main = acc + b
template <int D, int MODE>
__global__ __launch_bounds__(256) void agg_kernel(
    const float* __restrict__ h, const int* __restrict__ offs,
    const int* __restrict__ es, const float* __restrict__ ewr,
    const float* __restrict__ bias, const float* __restrict__ x1in,
    float* __restrict__ out_main, float* __restrict__ out_x1, int n) {
  const int lane = threadIdx.x & 63;
  const int node = blockIdx.x * 4 + (threadIdx.x >> 6);
  if (node >= n) return;
  const int s0 = offs[node];
  const int s1 = offs[node + 1];
  if (D == 128) {
    float ax = 0.f, ay = 0.f;
    for (int e = s0; e < s1; ++e) {
      int s = es[e];
      float w = ewr[e];
      float2 v = *(const float2*)&h[(size_t)s * 128 + lane * 2];
      ax = fmaf(w, v.x, ax);
      ay = fmaf(w, v.y, ay);
    }
    float2 b = *(const float2*)&bias[lane * 2];
    float vx = ax + b.x, vy = ay + b.y;
    size_t o = (size_t)node * 128 + lane * 2;
    if (MODE == 0) {
      float2 x1v; x1v.x = vx; x1v.y = vy;
      *(float2*)&out_x1[o] = x1v;
      float2 hn; hn.x = vx + relu_f(vx); hn.y = vy + relu_f(vy);
      *(float2*)&out_main[o] = hn;
    } else {
      float2 x1v = *(const float2*)&x1in[o];
      float2 hn; hn.x = x1v.x + relu_f(vx); hn.y = x1v.y + relu_f(vy);
      *(float2*)&out_main[o] = hn;
    }
  } else {  // D == 64
    float a = 0.f;
    for (int e = s0; e < s1; ++e)
      a = fmaf(ewr[e], h[(size_t)es[e] * 64 + lane], a);
    out_main[(size_t)node * 64 + lane] = a + bias[lane];
  }
}

extern "C" void kernel_launch(void* const* d_in, const int* in_sizes, int n_in,
                              void* d_out, int out_size, void* d_ws, size_t ws_size,
                              hipStream_t stream) {
  const float* x  = (const float*)d_in[0];
  const int*   ei = (const int*)d_in[1];
  const float* ew = (const float*)d_in[2];
  const float* W1 = (const float*)d_in[3];
  const float* b1 = (const float*)d_in[4];
  const float* W2 = (const float*)d_in[5];
  const float* b2 = (const float*)d_in[6];
  const float* W3 = (const float*)d_in[7];
  const float* b3 = (const float*)d_in[8];
  const int N = in_sizes[0] / 128;   // 50000
  const int E = in_sizes[2];         // 800000
  const int* src = ei;
  const int* dst = ei + E;

  char* p = (char*)d_ws;
  auto alloc = [&](size_t bytes) {
    void* q = (void*)p;
    p += (bytes + 511) & ~(size_t)511;
    return q;
  };
  int*   deg  = (int*)alloc((size_t)N * 4);
  int*   offs = (int*)alloc((size_t)(N + 1) * 4);
  int*   cur  = (int*)alloc((size_t)N * 4);
  int*   es   = (int*)alloc((size_t)E * 4);
  float* ewr  = (float*)alloc((size_t)E * 4);
  float* bufA = (float*)alloc((size_t)N * 128 * 4);  // mm outputs
  float* bufB = (float*)alloc((size_t)N * 128 * 4);  // x1 residual
  float* bufC = (float*)alloc((size_t)N * 128 * 4);  // next-layer input
  (void)ws_size; (void)n_in; (void)out_size;

  // Build CSR by destination
  hipMemsetAsync(deg, 0, (size_t)N * 4, stream);
  count_kernel<<<(E + 255) / 256, 256, 0, stream>>>(dst, deg, E);
  scan_kernel<<<1, 1024, 0, stream>>>(deg, offs, cur, N);
  fill_kernel<<<(E + 255) / 256, 256, 0, stream>>>(src, dst, ew, cur, es, ewr, E);

  const int mmGrid = (N + 63) / 64;
  const int aggGrid = (N + 3) / 4;

  // Layer 1
  mm_kernel<128><<<mmGrid, 256, 0, stream>>>(x, W1, bufA, N);
  agg_kernel<128, 0><<<aggGrid, 256, 0, stream>>>(bufA, offs, es, ewr, b1, nullptr,
                                                  bufC, bufB, N);
  // Layer 2
  mm_kernel<128><<<mmGrid, 256, 0, stream>>>(bufC, W2, bufA, N);
  agg_kernel<128, 1><<<aggGrid, 256, 0, stream>>>(bufA, offs, es, ewr, b2, bufB,
                                                  bufC, nullptr, N);
  // Layer 3
  mm_kernel<64><<<mmGrid, 256, 0, stream>>>(bufC, W3, bufA, N);
  agg_kernel<64, 2><<<aggGrid, 256, 0, stream>>>(bufA, offs, es, ewr, b3, nullptr,
                                                 (float*)d_out, nullptr, N);
}

// Round 2
// 411.720 us; speedup vs baseline: 1.4358x; 1.4358x over previous
//
#include <hip/hip_runtime.h>

// ---------------------------------------------------------------------------
// QGCN forward: 3 GCN layers (see round-0 header).
// Round 1: hierarchical scan (was 91us single-block), float4 dual-edge agg.
// ---------------------------------------------------------------------------

__device__ __forceinline__ float relu_f(float v) { return v > 0.f ? v : 0.f; }

__global__ __launch_bounds__(256) void count_kernel(const int* __restrict__ dst,
                                                    int* __restrict__ deg, int E) {
  int e = blockIdx.x * 256 + threadIdx.x;
  if (e < E) atomicAdd(&deg[dst[e]], 1);
}

// --- hierarchical exclusive scan over n ints ---------------------------------
// k1: per-1024-chunk sums
__global__ __launch_bounds__(256) void block_sum_kernel(const int* __restrict__ deg,
                                                        int* __restrict__ bsum, int n) {
  __shared__ int s[4];
  int base = blockIdx.x * 1024;
  int t = threadIdx.x;
  int v = 0;
  for (int i = t; i < 1024; i += 256) {
    int idx = base + i;
    if (idx < n) v += deg[idx];
  }
#pragma unroll
  for (int off = 32; off > 0; off >>= 1) v += __shfl_down(v, off, 64);
  if ((t & 63) == 0) s[t >> 6] = v;
  __syncthreads();
  if (t == 0) bsum[blockIdx.x] = s[0] + s[1] + s[2] + s[3];
}

// k2: exclusive scan of nb partial sums, single wave (handles nb>64 via carry)
__global__ __launch_bounds__(64) void scan_partials_kernel(int* __restrict__ bsum,
                                                           int nb) {
  int lane = threadIdx.x;
  int carry = 0;
  for (int base = 0; base < nb; base += 64) {
    int i = base + lane;
    int orig = (i < nb) ? bsum[i] : 0;
    int v = orig;
#pragma unroll
    for (int off = 1; off < 64; off <<= 1) {
      int y = __shfl_up(v, off, 64);
      if (lane >= off) v += y;
    }
    int total = __shfl(v, 63, 64);
    if (i < nb) bsum[i] = carry + v - orig;  // exclusive
    carry += total;
  }
}

// k3: per-chunk local scan + chunk offset -> offs/cur; last element writes offs[n]
__global__ __launch_bounds__(1024) void block_scan_kernel(
    const int* __restrict__ deg, const int* __restrict__ bsum,
    int* __restrict__ offs, int* __restrict__ cur, int n) {
  __shared__ int buf[1024];
  int t = threadIdx.x;
  int i = blockIdx.x * 1024 + t;
  int v = (i < n) ? deg[i] : 0;
  buf[t] = v;
  __syncthreads();
#pragma unroll
  for (int off = 1; off < 1024; off <<= 1) {
    int y = (t >= off) ? buf[t - off] : 0;
    __syncthreads();
    buf[t] += y;
    __syncthreads();
  }
  int ex = bsum[blockIdx.x] + buf[t] - v;
  if (i < n) {
    offs[i] = ex;
    cur[i] = ex;
    if (i == n - 1) offs[n] = ex + v;
  }
}

__global__ __launch_bounds__(256) void fill_kernel(const int* __restrict__ src,
                                                   const int* __restrict__ dst,
                                                   const float* __restrict__ ew,
                                                   int* __restrict__ cur,
                                                   int* __restrict__ es,
                                                   float* __restrict__ ewr, int E) {
  int e = blockIdx.x * 256 + threadIdx.x;
  if (e < E) {
    int d = dst[e];
    int pos = atomicAdd(&cur[d], 1);
    es[pos] = src[e];
    ewr[pos] = ew[e];
  }
}

// C[N,DOUT] = A[N,128] @ W[128,DOUT].  Block = 64 rows x DOUT cols.
template <int DOUT>
__global__ __launch_bounds__(256) void mm_kernel(const float* __restrict__ A,
                                                 const float* __restrict__ W,
                                                 float* __restrict__ C, int N) {
  constexpr int K = 128;
  constexpr int KT = 32;
  constexpr int TC = DOUT / 16;
  constexpr int ASTRIDE = KT + 4;
  __shared__ float Ws[KT * DOUT];
  __shared__ float As[64 * ASTRIDE];
  const int t = threadIdx.x;
  const int tx = t & 15;
  const int ty = t >> 4;
  const int row0 = blockIdx.x * 64;

  float acc[4][TC];
#pragma unroll
  for (int r = 0; r < 4; ++r)
#pragma unroll
    for (int c = 0; c < TC; ++c) acc[r][c] = 0.f;

  for (int k0 = 0; k0 < K; k0 += KT) {
    __syncthreads();
    {
      int r = t >> 2;
      int c = (t & 3) * 8;
      int row = row0 + r;
      if (row >= N) row = N - 1;
      const float* s = &A[(size_t)row * K + k0 + c];
      float4 v0 = *(const float4*)s;
      float4 v1 = *(const float4*)(s + 4);
      float* d = &As[r * ASTRIDE + c];
      *(float4*)d = v0;
      *(float4*)(d + 4) = v1;
    }
#pragma unroll
    for (int i = t * 4; i < KT * DOUT; i += 1024) {
      *(float4*)&Ws[i] = *(const float4*)&W[k0 * DOUT + i];
    }
    __syncthreads();
#pragma unroll
    for (int kk = 0; kk < KT; ++kk) {
      float a[4];
#pragma unroll
      for (int r = 0; r < 4; ++r) a[r] = As[(ty * 4 + r) * ASTRIDE + kk];
      float w[TC];
#pragma unroll
      for (int c = 0; c < TC; c += 4)
        *(float4*)&w[c] = *(const float4*)&Ws[kk * DOUT + tx * TC + c];
#pragma unroll
      for (int r = 0; r < 4; ++r)
#pragma unroll
        for (int c = 0; c < TC; ++c) acc[r][c] = fmaf(a[r], w[c], acc[r][c]);
    }
  }
#pragma unroll
  for (int r = 0; r < 4; ++r) {
    int row = row0 + ty * 4 + r;
    if (row < N) {
#pragma unroll
      for (int c = 0; c < TC; c += 4) {
        float4 v;
        v.x = acc[r][c + 0]; v.y = acc[r][c + 1];
        v.z = acc[r][c + 2]; v.w = acc[r][c + 3];
        *(float4*)&C[(size_t)row * DOUT + tx * TC + c] = v;
      }
    }
  }
}

// Gather aggregation, D=128: one wave per node, 32 lanes x float4 per row,
// two edges in flight (halves), reduced via shfl_xor(32).
// MODE 0: x1 = acc+b -> out_x1 = x1, out_main = x1 + relu(x1)
// MODE 1: t  = acc+b -> out_main = x1in + relu(t)
template <int MODE>
__global__ __launch_bounds__(256) void agg128_kernel(
    const float* __restrict__ h, const int* __restrict__ offs,
    const int* __restrict__ es, const float* __restrict__ ewr,
    const float* __restrict__ bias, const float* __restrict__ x1in,
    float* __restrict__ out_main, float* __restrict__ out_x1, int n) {
  const int lane = threadIdx.x & 63;
  const int half = lane >> 5;       // 0/1: which edge of the pair
  const int fl = lane & 31;         // feature group: floats [fl*4, fl*4+4)
  const int node = blockIdx.x * 4 + (threadIdx.x >> 6);
  if (node >= n) return;
  const int s0 = offs[node];
  const int s1 = offs[node + 1];
  float4 acc = {0.f, 0.f, 0.f, 0.f};
  for (int e = s0 + half; e < s1; e += 2) {
    int s = es[e];
    float w = ewr[e];
    float4 v = *(const float4*)&h[(size_t)s * 128 + fl * 4];
    acc.x = fmaf(w, v.x, acc.x);
    acc.y = fmaf(w, v.y, acc.y);
    acc.z = fmaf(w, v.z, acc.z);
    acc.w = fmaf(w, v.w, acc.w);
  }
  acc.x += __shfl_xor(acc.x, 32, 64);
  acc.y += __shfl_xor(acc.y, 32, 64);
  acc.z += __shfl_xor(acc.z, 32, 64);
  acc.w += __shfl_xor(acc.w, 32, 64);
  if (half == 0) {
    float4 b = *(const float4*)&bias[fl * 4];
    float4 v;
    v.x = acc.x + b.x; v.y = acc.y + b.y; v.z = acc.z + b.z; v.w = acc.w + b.w;
    size_t o = (size_t)node * 128 + fl * 4;
    if (MODE == 0) {
      *(float4*)&out_x1[o] = v;
      float4 hn;
      hn.x = v.x + relu_f(v.x); hn.y = v.y + relu_f(v.y);
      hn.z = v.z + relu_f(v.z); hn.w = v.w + relu_f(v.w);
      *(float4*)&out_main[o] = hn;
    } else {
      float4 x1v = *(const float4*)&x1in[o];
      float4 hn;
      hn.x = x1v.x + relu_f(v.x); hn.y = x1v.y + relu_f(v.y);
      hn.z = x1v.z + relu_f(v.z); hn.w = x1v.w + relu_f(v.w);
      *(float4*)&out_main[o] = hn;
    }
  }
}

// D=64 final layer: 16 lanes x float4 per row, four edges in flight.
__global__ __launch_bounds__(256) void agg64_kernel(
    const float* __restrict__ h, const int* __restrict__ offs,
    const int* __restrict__ es, const float* __restrict__ ewr,
    const float* __restrict__ bias, float* __restrict__ out, int n) {
  const int lane = threadIdx.x & 63;
  const int quad = lane >> 4;       // 0..3: which edge of the group
  const int fl = lane & 15;         // floats [fl*4, fl*4+4)
  const int node = blockIdx.x * 4 + (threadIdx.x >> 6);
  if (node >= n) return;
  const int s0 = offs[node];
  const int s1 = offs[node + 1];
  float4 acc = {0.f, 0.f, 0.f, 0.f};
  for (int e = s0 + quad; e < s1; e += 4) {
    int s = es[e];
    float w = ewr[e];
    float4 v = *(const float4*)&h[(size_t)s * 64 + fl * 4];
    acc.x = fmaf(w, v.x, acc.x);
    acc.y = fmaf(w, v.y, acc.y);
    acc.z = fmaf(w, v.z, acc.z);
    acc.w = fmaf(w, v.w, acc.w);
  }
#pragma unroll
  for (int m = 16; m < 64; m <<= 1) {
    acc.x += __shfl_xor(acc.x, m, 64);
    acc.y += __shfl_xor(acc.y, m, 64);
    acc.z += __shfl_xor(acc.z, m, 64);
    acc.w += __shfl_xor(acc.w, m, 64);
  }
  if (quad == 0) {
    float4 b = *(const float4*)&bias[fl * 4];
    float4 v;
    v.x = acc.x + b.x; v.y = acc.y + b.y; v.z = acc.z + b.z; v.w = acc.w + b.w;
    *(float4*)&out[(size_t)node * 64 + fl * 4] = v;
  }
}

extern "C" void kernel_launch(void* const* d_in, const int* in_sizes, int n_in,
                              void* d_out, int out_size, void* d_ws, size_t ws_size,
                              hipStream_t stream) {
  const float* x  = (const float*)d_in[0];
  const int*   ei = (const int*)d_in[1];
  const float* ew = (const float*)d_in[2];
  const float* W1 = (const float*)d_in[3];
  const float* b1 = (const float*)d_in[4];
  const float* W2 = (const float*)d_in[5];
  const float* b2 = (const float*)d_in[6];
  const float* W3 = (const float*)d_in[7];
  const float* b3 = (const float*)d_in[8];
  const int N = in_sizes[0] / 128;   // 50000
  const int E = in_sizes[2];         // 800000
  const int* src = ei;
  const int* dst = ei + E;

  char* p = (char*)d_ws;
  auto alloc = [&](size_t bytes) {
    void* q = (void*)p;
    p += (bytes + 511) & ~(size_t)511;
    return q;
  };
  int*   deg  = (int*)alloc((size_t)N * 4);
  int*   offs = (int*)alloc((size_t)(N + 1) * 4);
  int*   cur  = (int*)alloc((size_t)N * 4);
  int*   bsum = (int*)alloc(4096);
  int*   es   = (int*)alloc((size_t)E * 4);
  float* ewr  = (float*)alloc((size_t)E * 4);
  float* bufA = (float*)alloc((size_t)N * 128 * 4);
  float* bufB = (float*)alloc((size_t)N * 128 * 4);
  float* bufC = (float*)alloc((size_t)N * 128 * 4);
  (void)ws_size; (void)n_in; (void)out_size;

  const int nChunks = (N + 1023) / 1024;

  // Build CSR by destination
  hipMemsetAsync(deg, 0, (size_t)N * 4, stream);
  count_kernel<<<(E + 255) / 256, 256, 0, stream>>>(dst, deg, E);
  block_sum_kernel<<<nChunks, 256, 0, stream>>>(deg, bsum, N);
  scan_partials_kernel<<<1, 64, 0, stream>>>(bsum, nChunks);
  block_scan_kernel<<<nChunks, 1024, 0, stream>>>(deg, bsum, offs, cur, N);
  fill_kernel<<<(E + 255) / 256, 256, 0, stream>>>(src, dst, ew, cur, es, ewr, E);

  const int mmGrid = (N + 63) / 64;
  const int aggGrid = (N + 3) / 4;

  // Layer 1
  mm_kernel<128><<<mmGrid, 256, 0, stream>>>(x, W1, bufA, N);
  agg128_kernel<0><<<aggGrid, 256, 0, stream>>>(bufA, offs, es, ewr, b1, nullptr,
                                                bufC, bufB, N);
  // Layer 2
  mm_kernel<128><<<mmGrid, 256, 0, stream>>>(bufC, W2, bufA, N);
  agg128_kernel<1><<<aggGrid, 256, 0, stream>>>(bufA, offs, es, ewr, b2, bufB,
                                                bufC, nullptr, N);
  // Layer 3
  mm_kernel<64><<<mmGrid, 256, 0, stream>>>(bufC, W3, bufA, N);
  agg64_kernel<<<aggGrid, 256, 0, stream>>>(bufA, offs, es, ewr, b3, (float*)d_out, N);
}

// Round 3
// 318.167 us; speedup vs baseline: 1.8580x; 1.2940x over previous
//
#include <hip/hip_runtime.h>

// ---------------------------------------------------------------------------
// QGCN forward, round 3: bf16 everywhere internal.
//  - mm via MFMA 16x16x32 bf16 (fp32 accum), weights pre-packed to frag order
//  - aggregation gathers bf16 rows (256B / 128B) -> halved gather traffic
//  - CSR build (histogram -> hierarchical scan -> fill) unchanged
// Numerics: bf16 storage + MFMA inputs, fp32 accumulation throughout.
// ---------------------------------------------------------------------------

typedef __attribute__((ext_vector_type(8))) short short8;
typedef __attribute__((ext_vector_type(4))) float floatx4;

__device__ __forceinline__ float relu_f(float v) { return v > 0.f ? v : 0.f; }

__device__ __forceinline__ unsigned short f2bf(float f) {
  union { float f; unsigned int i; } v; v.f = f;
  unsigned int r = v.i + 0x7fffu + ((v.i >> 16) & 1u);  // RNE
  return (unsigned short)(r >> 16);
}
__device__ __forceinline__ unsigned int f2bf2(float lo, float hi) {
  return (unsigned int)f2bf(lo) | ((unsigned int)f2bf(hi) << 16);
}
__device__ __forceinline__ float bflo(unsigned int u) {
  union { unsigned int i; float f; } v; v.i = u << 16; return v.f;
}
__device__ __forceinline__ float bfhi(unsigned int u) {
  union { unsigned int i; float f; } v; v.i = u & 0xffff0000u; return v.f;
}

// ---------------- CSR build ----------------
__global__ __launch_bounds__(256) void count_kernel(const int* __restrict__ dst,
                                                    int* __restrict__ deg, int E) {
  int e = blockIdx.x * 256 + threadIdx.x;
  if (e < E) atomicAdd(&deg[dst[e]], 1);
}

__global__ __launch_bounds__(256) void block_sum_kernel(const int* __restrict__ deg,
                                                        int* __restrict__ bsum, int n) {
  __shared__ int s[4];
  int base = blockIdx.x * 1024;
  int t = threadIdx.x;
  int v = 0;
  for (int i = t; i < 1024; i += 256) {
    int idx = base + i;
    if (idx < n) v += deg[idx];
  }
#pragma unroll
  for (int off = 32; off > 0; off >>= 1) v += __shfl_down(v, off, 64);
  if ((t & 63) == 0) s[t >> 6] = v;
  __syncthreads();
  if (t == 0) bsum[blockIdx.x] = s[0] + s[1] + s[2] + s[3];
}

__global__ __launch_bounds__(64) void scan_partials_kernel(int* __restrict__ bsum,
                                                           int nb) {
  int lane = threadIdx.x;
  int carry = 0;
  for (int base = 0; base < nb; base += 64) {
    int i = base + lane;
    int orig = (i < nb) ? bsum[i] : 0;
    int v = orig;
#pragma unroll
    for (int off = 1; off < 64; off <<= 1) {
      int y = __shfl_up(v, off, 64);
      if (lane >= off) v += y;
    }
    int total = __shfl(v, 63, 64);
    if (i < nb) bsum[i] = carry + v - orig;
    carry += total;
  }
}

__global__ __launch_bounds__(1024) void block_scan_kernel(
    const int* __restrict__ deg, const int* __restrict__ bsum,
    int* __restrict__ offs, int* __restrict__ cur, int n) {
  __shared__ int buf[1024];
  int t = threadIdx.x;
  int i = blockIdx.x * 1024 + t;
  int v = (i < n) ? deg[i] : 0;
  buf[t] = v;
  __syncthreads();
#pragma unroll
  for (int off = 1; off < 1024; off <<= 1) {
    int y = (t >= off) ? buf[t - off] : 0;
    __syncthreads();
    buf[t] += y;
    __syncthreads();
  }
  int ex = bsum[blockIdx.x] + buf[t] - v;
  if (i < n) {
    offs[i] = ex;
    cur[i] = ex;
    if (i == n - 1) offs[n] = ex + v;
  }
}

__global__ __launch_bounds__(256) void fill_kernel(const int* __restrict__ src,
                                                   const int* __restrict__ dst,
                                                   const float* __restrict__ ew,
                                                   int* __restrict__ cur,
                                                   int* __restrict__ es,
                                                   float* __restrict__ ewr, int E) {
  int e = blockIdx.x * 256 + threadIdx.x;
  if (e < E) {
    int d = dst[e];
    int pos = atomicAdd(&cur[d], 1);
    es[pos] = src[e];
    ewr[pos] = ew[e];
  }
}

// ---------------- weight pack: W[k][n] fp32 -> frag-order bf16 --------------
// P[((cg*4 + kc)*64 + lane)*8 + j] = bf16( W[kc*32 + (lane>>4)*8 + j][cg*16 + (lane&15)] )
__global__ __launch_bounds__(256) void pack_w_kernel(
    const float* __restrict__ W1, const float* __restrict__ W2,
    const float* __restrict__ W3, unsigned short* __restrict__ P1,
    unsigned short* __restrict__ P2, unsigned short* __restrict__ P3) {
  int idx = blockIdx.x * 256 + threadIdx.x;  // 40960 total
  const float* W; unsigned short* P; int dout, li;
  if (idx < 16384)      { W = W1; P = P1; dout = 128; li = idx; }
  else if (idx < 32768) { W = W2; P = P2; dout = 128; li = idx - 16384; }
  else if (idx < 40960) { W = W3; P = P3; dout = 64;  li = idx - 32768; }
  else return;
  int j = li & 7, lane = (li >> 3) & 63, kc = (li >> 9) & 3, cg = li >> 11;
  int k = kc * 32 + ((lane >> 4) << 3) + j;
  int ncol = cg * 16 + (lane & 15);
  P[li] = f2bf(W[k * dout + ncol]);
}

// ---------------- MFMA matmul: C[N,DOUT](bf16) = A[N,128] @ W ----------------
// block = 256 thr = 4 waves, 64 rows. K=128 in one LDS tile (pad +8 bf16/row).
template <int DOUT, bool A_IS_F32>
__global__ __launch_bounds__(256) void mm_mfma_kernel(
    const void* __restrict__ Ap, const unsigned short* __restrict__ Wpack,
    unsigned short* __restrict__ C, int N) {
  constexpr int CG = DOUT / 16;
  constexpr int AS = 136;  // bf16 elems per LDS row (128 + 8 pad)
  __shared__ unsigned short As[64 * AS];
  const int t = threadIdx.x;
  const int lane = t & 63;
  const int w = t >> 6;
  const int row0 = blockIdx.x * 64;

  {  // stage A: thread t -> row t>>2, cols (t&3)*32 .. +32
    int r = t >> 2, c0 = (t & 3) * 32;
    int row = row0 + r;
    if (row >= N) row = N - 1;
    if (A_IS_F32) {
      const float* A = (const float*)Ap;
      const float* s = &A[(size_t)row * 128 + c0];
      unsigned short* d = &As[r * AS + c0];
#pragma unroll
      for (int i = 0; i < 32; i += 8) {
        float4 v0 = *(const float4*)(s + i);
        float4 v1 = *(const float4*)(s + i + 4);
        uint4 o;
        o.x = f2bf2(v0.x, v0.y); o.y = f2bf2(v0.z, v0.w);
        o.z = f2bf2(v1.x, v1.y); o.w = f2bf2(v1.z, v1.w);
        *(uint4*)(d + i) = o;
      }
    } else {
      const unsigned short* A = (const unsigned short*)Ap;
      const uint4* s = (const uint4*)&A[(size_t)row * 128 + c0];
      unsigned short* d = &As[r * AS + c0];
#pragma unroll
      for (int i = 0; i < 4; ++i) *(uint4*)(d + i * 8) = s[i];
    }
  }
  __syncthreads();

  const int m = lane & 15, q = lane >> 4;
  floatx4 acc[CG];
#pragma unroll
  for (int cg = 0; cg < CG; ++cg) acc[cg] = (floatx4){0.f, 0.f, 0.f, 0.f};

#pragma unroll
  for (int kc = 0; kc < 4; ++kc) {
    short8 a = *(const short8*)&As[(w * 16 + m) * AS + kc * 32 + q * 8];
#pragma unroll
    for (int cg = 0; cg < CG; ++cg) {
      short8 b = *(const short8*)&Wpack[((cg * 4 + kc) * 64 + lane) * 8];
      acc[cg] = __builtin_amdgcn_mfma_f32_16x16x32_bf16(a, b, acc[cg], 0, 0, 0);
    }
  }

  // C/D layout: col = lane&15 (=m), row = q*4 + reg   [verified m89/m91]
#pragma unroll
  for (int cg = 0; cg < CG; ++cg) {
#pragma unroll
    for (int r = 0; r < 4; ++r) {
      int row = row0 + w * 16 + q * 4 + r;
      if (row < N) C[(size_t)row * DOUT + cg * 16 + m] = f2bf(acc[cg][r]);
    }
  }
}

// ---------------- aggregation, D=128 bf16 rows ----------------
// wave/node; 4 edge-groups x 16 lanes; lane covers 8 feats (16B load).
// MODE 0: x1 = acc+b -> out_x1 = x1 (bf16), out_main = x1+relu(x1) (bf16)
// MODE 1: t  = acc+b -> out_main = x1in + relu(t) (bf16)
template <int MODE>
__global__ __launch_bounds__(256) void agg128_bf16_kernel(
    const unsigned short* __restrict__ h, const int* __restrict__ offs,
    const int* __restrict__ es, const float* __restrict__ ewr,
    const float* __restrict__ bias, const unsigned short* __restrict__ x1in,
    unsigned short* __restrict__ out_main, unsigned short* __restrict__ out_x1,
    int n) {
  const int lane = threadIdx.x & 63;
  const int g = lane >> 4;
  const int fl = lane & 15;
  const int node = blockIdx.x * 4 + (threadIdx.x >> 6);
  if (node >= n) return;
  const int s0 = offs[node];
  const int s1 = offs[node + 1];
  float acc[8] = {0.f, 0.f, 0.f, 0.f, 0.f, 0.f, 0.f, 0.f};
  for (int e = s0 + g; e < s1; e += 4) {
    int s = es[e];
    float wt = ewr[e];
    uint4 v = *(const uint4*)&h[(size_t)s * 128 + fl * 8];
    acc[0] = fmaf(wt, bflo(v.x), acc[0]);
    acc[1] = fmaf(wt, bfhi(v.x), acc[1]);
    acc[2] = fmaf(wt, bflo(v.y), acc[2]);
    acc[3] = fmaf(wt, bfhi(v.y), acc[3]);
    acc[4] = fmaf(wt, bflo(v.z), acc[4]);
    acc[5] = fmaf(wt, bfhi(v.z), acc[5]);
    acc[6] = fmaf(wt, bflo(v.w), acc[6]);
    acc[7] = fmaf(wt, bfhi(v.w), acc[7]);
  }
#pragma unroll
  for (int msk = 16; msk < 64; msk <<= 1)
#pragma unroll
    for (int i = 0; i < 8; ++i) acc[i] += __shfl_xor(acc[i], msk, 64);
  if (g == 0) {
    float4 b0 = *(const float4*)&bias[fl * 8];
    float4 b1 = *(const float4*)&bias[fl * 8 + 4];
    float v[8];
    v[0] = acc[0] + b0.x; v[1] = acc[1] + b0.y; v[2] = acc[2] + b0.z;
    v[3] = acc[3] + b0.w; v[4] = acc[4] + b1.x; v[5] = acc[5] + b1.y;
    v[6] = acc[6] + b1.z; v[7] = acc[7] + b1.w;
    size_t o = (size_t)node * 128 + fl * 8;
    float hn[8];
    if (MODE == 0) {
      uint4 xo;
      xo.x = f2bf2(v[0], v[1]); xo.y = f2bf2(v[2], v[3]);
      xo.z = f2bf2(v[4], v[5]); xo.w = f2bf2(v[6], v[7]);
      *(uint4*)&out_x1[o] = xo;
#pragma unroll
      for (int i = 0; i < 8; ++i) hn[i] = v[i] + relu_f(v[i]);
    } else {
      uint4 x1v = *(const uint4*)&x1in[o];
      float xv[8] = {bflo(x1v.x), bfhi(x1v.x), bflo(x1v.y), bfhi(x1v.y),
                     bflo(x1v.z), bfhi(x1v.z), bflo(x1v.w), bfhi(x1v.w)};
#pragma unroll
      for (int i = 0; i < 8; ++i) hn[i] = xv[i] + relu_f(v[i]);
    }
    uint4 ho;
    ho.x = f2bf2(hn[0], hn[1]); ho.y = f2bf2(hn[2], hn[3]);
    ho.z = f2bf2(hn[4], hn[5]); ho.w = f2bf2(hn[6], hn[7]);
    *(uint4*)&out_main[o] = ho;
  }
}

// ---------------- aggregation, D=64 bf16 rows -> fp32 out ----------------
// wave/node; 8 edge-groups x 8 lanes; lane covers 8 feats (16B load).
__global__ __launch_bounds__(256) void agg64_bf16_kernel(
    const unsigned short* __restrict__ h, const int* __restrict__ offs,
    const int* __restrict__ es, const float* __restrict__ ewr,
    const float* __restrict__ bias, float* __restrict__ out, int n) {
  const int lane = threadIdx.x & 63;
  const int g = lane >> 3;
  const int fl = lane & 7;
  const int node = blockIdx.x * 4 + (threadIdx.x >> 6);
  if (node >= n) return;
  const int s0 = offs[node];
  const int s1 = offs[node + 1];
  float acc[8] = {0.f, 0.f, 0.f, 0.f, 0.f, 0.f, 0.f, 0.f};
  for (int e = s0 + g; e < s1; e += 8) {
    int s = es[e];
    float wt = ewr[e];
    uint4 v = *(const uint4*)&h[(size_t)s * 64 + fl * 8];
    acc[0] = fmaf(wt, bflo(v.x), acc[0]);
    acc[1] = fmaf(wt, bfhi(v.x), acc[1]);
    acc[2] = fmaf(wt, bflo(v.y), acc[2]);
    acc[3] = fmaf(wt, bfhi(v.y), acc[3]);
    acc[4] = fmaf(wt, bflo(v.z), acc[4]);
    acc[5] = fmaf(wt, bfhi(v.z), acc[5]);
    acc[6] = fmaf(wt, bflo(v.w), acc[6]);
    acc[7] = fmaf(wt, bfhi(v.w), acc[7]);
  }
#pragma unroll
  for (int msk = 8; msk < 64; msk <<= 1)
#pragma unroll
    for (int i = 0; i < 8; ++i) acc[i] += __shfl_xor(acc[i], msk, 64);
  if (g == 0) {
    float4 b0 = *(const float4*)&bias[fl * 8];
    float4 b1 = *(const float4*)&bias[fl * 8 + 4];
    float4 o0, o1;
    o0.x = acc[0] + b0.x; o0.y = acc[1] + b0.y;
    o0.z = acc[2] + b0.z; o0.w = acc[3] + b0.w;
    o1.x = acc[4] + b1.x; o1.y = acc[5] + b1.y;
    o1.z = acc[6] + b1.z; o1.w = acc[7] + b1.w;
    size_t o = (size_t)node * 64 + fl * 8;
    *(float4*)&out[o] = o0;
    *(float4*)&out[o + 4] = o1;
  }
}

extern "C" void kernel_launch(void* const* d_in, const int* in_sizes, int n_in,
                              void* d_out, int out_size, void* d_ws, size_t ws_size,
                              hipStream_t stream) {
  const float* x  = (const float*)d_in[0];
  const int*   ei = (const int*)d_in[1];
  const float* ew = (const float*)d_in[2];
  const float* W1 = (const float*)d_in[3];
  const float* b1 = (const float*)d_in[4];
  const float* W2 = (const float*)d_in[5];
  const float* b2 = (const float*)d_in[6];
  const float* W3 = (const float*)d_in[7];
  const float* b3 = (const float*)d_in[8];
  const int N = in_sizes[0] / 128;   // 50000
  const int E = in_sizes[2];         // 800000
  const int* src = ei;
  const int* dst = ei + E;

  char* p = (char*)d_ws;
  auto alloc = [&](size_t bytes) {
    void* q = (void*)p;
    p += (bytes + 511) & ~(size_t)511;
    return q;
  };
  int*   deg  = (int*)alloc((size_t)N * 4);
  int*   offs = (int*)alloc((size_t)(N + 1) * 4);
  int*   cur  = (int*)alloc((size_t)N * 4);
  int*   bsum = (int*)alloc(4096);
  int*   es   = (int*)alloc((size_t)E * 4);
  float* ewr  = (float*)alloc((size_t)E * 4);
  unsigned short* hb  = (unsigned short*)alloc((size_t)N * 128 * 2);
  unsigned short* x1b = (unsigned short*)alloc((size_t)N * 128 * 2);
  unsigned short* cb  = (unsigned short*)alloc((size_t)N * 128 * 2);
  unsigned short* P1  = (unsigned short*)alloc(16384 * 2);
  unsigned short* P2  = (unsigned short*)alloc(16384 * 2);
  unsigned short* P3  = (unsigned short*)alloc(8192 * 2);
  (void)ws_size; (void)n_in; (void)out_size;

  const int nChunks = (N + 1023) / 1024;

  // CSR by destination
  hipMemsetAsync(deg, 0, (size_t)N * 4, stream);
  count_kernel<<<(E + 255) / 256, 256, 0, stream>>>(dst, deg, E);
  block_sum_kernel<<<nChunks, 256, 0, stream>>>(deg, bsum, N);
  scan_partials_kernel<<<1, 64, 0, stream>>>(bsum, nChunks);
  block_scan_kernel<<<nChunks, 1024, 0, stream>>>(deg, bsum, offs, cur, N);
  fill_kernel<<<(E + 255) / 256, 256, 0, stream>>>(src, dst, ew, cur, es, ewr, E);

  // weight packing (frag order, bf16)
  pack_w_kernel<<<160, 256, 0, stream>>>(W1, W2, W3, P1, P2, P3);

  const int mmGrid = (N + 63) / 64;
  const int aggGrid = (N + 3) / 4;

  // Layer 1
  mm_mfma_kernel<128, true><<<mmGrid, 256, 0, stream>>>(x, P1, hb, N);
  agg128_bf16_kernel<0><<<aggGrid, 256, 0, stream>>>(hb, offs, es, ewr, b1,
                                                     nullptr, cb, x1b, N);
  // Layer 2
  mm_mfma_kernel<128, false><<<mmGrid, 256, 0, stream>>>(cb, P2, hb, N);
  agg128_bf16_kernel<1><<<aggGrid, 256, 0, stream>>>(hb, offs, es, ewr, b2,
                                                     x1b, cb, nullptr, N);
  // Layer 3
  mm_mfma_kernel<64, false><<<mmGrid, 256, 0, stream>>>(cb, P3, hb, N);
  agg64_bf16_kernel<<<aggGrid, 256, 0, stream>>>(hb, offs, es, ewr, b3,
                                                 (float*)d_out, N);
}

// Round 5
// 306.967 us; speedup vs baseline: 1.9258x; 1.0365x over previous
//
#include <hip/hip_runtime.h>

// ---------------------------------------------------------------------------
// QGCN forward, round 5.
//  - CSR record packed (src,w) int2: fill does ONE 8B scatter per edge.
//  - agg: round-3 proven per-group broadcast loads (NO shfl broadcast — the
//    round-4 cooperative+shfl variant miscomputed; shfl from lanes inactive
//    in a divergent loop is undefined). int2 record + unroll-2.
//  - mm via MFMA 16x16x32 bf16 (fp32 accum), weights pre-packed.
// ---------------------------------------------------------------------------

typedef __attribute__((ext_vector_type(8))) short short8;
typedef __attribute__((ext_vector_type(4))) float floatx4;

__device__ __forceinline__ float relu_f(float v) { return v > 0.f ? v : 0.f; }

__device__ __forceinline__ unsigned short f2bf(float f) {
  union { float f; unsigned int i; } v; v.f = f;
  unsigned int r = v.i + 0x7fffu + ((v.i >> 16) & 1u);  // RNE
  return (unsigned short)(r >> 16);
}
__device__ __forceinline__ unsigned int f2bf2(float lo, float hi) {
  return (unsigned int)f2bf(lo) | ((unsigned int)f2bf(hi) << 16);
}
__device__ __forceinline__ float bflo(unsigned int u) {
  union { unsigned int i; float f; } v; v.i = u << 16; return v.f;
}
__device__ __forceinline__ float bfhi(unsigned int u) {
  union { unsigned int i; float f; } v; v.i = u & 0xffff0000u; return v.f;
}

// ---------------- CSR build ----------------
__global__ __launch_bounds__(256) void count_kernel(const int* __restrict__ dst,
                                                    int* __restrict__ deg, int E) {
  int e = blockIdx.x * 256 + threadIdx.x;
  if (e < E) atomicAdd(&deg[dst[e]], 1);
}

__global__ __launch_bounds__(256) void block_sum_kernel(const int* __restrict__ deg,
                                                        int* __restrict__ bsum, int n) {
  __shared__ int s[4];
  int base = blockIdx.x * 1024;
  int t = threadIdx.x;
  int v = 0;
  for (int i = t; i < 1024; i += 256) {
    int idx = base + i;
    if (idx < n) v += deg[idx];
  }
#pragma unroll
  for (int off = 32; off > 0; off >>= 1) v += __shfl_down(v, off, 64);
  if ((t & 63) == 0) s[t >> 6] = v;
  __syncthreads();
  if (t == 0) bsum[blockIdx.x] = s[0] + s[1] + s[2] + s[3];
}

__global__ __launch_bounds__(64) void scan_partials_kernel(int* __restrict__ bsum,
                                                           int nb) {
  int lane = threadIdx.x;
  int carry = 0;
  for (int base = 0; base < nb; base += 64) {
    int i = base + lane;
    int orig = (i < nb) ? bsum[i] : 0;
    int v = orig;
#pragma unroll
    for (int off = 1; off < 64; off <<= 1) {
      int y = __shfl_up(v, off, 64);
      if (lane >= off) v += y;
    }
    int total = __shfl(v, 63, 64);
    if (i < nb) bsum[i] = carry + v - orig;
    carry += total;
  }
}

__global__ __launch_bounds__(1024) void block_scan_kernel(
    const int* __restrict__ deg, const int* __restrict__ bsum,
    int* __restrict__ offs, int* __restrict__ cur, int n) {
  __shared__ int buf[1024];
  int t = threadIdx.x;
  int i = blockIdx.x * 1024 + t;
  int v = (i < n) ? deg[i] : 0;
  buf[t] = v;
  __syncthreads();
#pragma unroll
  for (int off = 1; off < 1024; off <<= 1) {
    int y = (t >= off) ? buf[t - off] : 0;
    __syncthreads();
    buf[t] += y;
    __syncthreads();
  }
  int ex = bsum[blockIdx.x] + buf[t] - v;
  if (i < n) {
    offs[i] = ex;
    cur[i] = ex;
    if (i == n - 1) offs[n] = ex + v;
  }
}

__global__ __launch_bounds__(256) void fill_kernel(const int* __restrict__ src,
                                                   const int* __restrict__ dst,
                                                   const float* __restrict__ ew,
                                                   int* __restrict__ cur,
                                                   int2* __restrict__ esw, int E) {
  int e = blockIdx.x * 256 + threadIdx.x;
  if (e < E) {
    int d = dst[e];
    int pos = atomicAdd(&cur[d], 1);
    int2 rec;
    rec.x = src[e];
    rec.y = __float_as_int(ew[e]);
    esw[pos] = rec;  // single 8B scattered store
  }
}

// ---------------- weight pack: W[k][n] fp32 -> frag-order bf16 --------------
__global__ __launch_bounds__(256) void pack_w_kernel(
    const float* __restrict__ W1, const float* __restrict__ W2,
    const float* __restrict__ W3, unsigned short* __restrict__ P1,
    unsigned short* __restrict__ P2, unsigned short* __restrict__ P3) {
  int idx = blockIdx.x * 256 + threadIdx.x;  // 40960 total
  const float* W; unsigned short* P; int dout, li;
  if (idx < 16384)      { W = W1; P = P1; dout = 128; li = idx; }
  else if (idx < 32768) { W = W2; P = P2; dout = 128; li = idx - 16384; }
  else if (idx < 40960) { W = W3; P = P3; dout = 64;  li = idx - 32768; }
  else return;
  int j = li & 7, lane = (li >> 3) & 63, kc = (li >> 9) & 3, cg = li >> 11;
  int k = kc * 32 + ((lane >> 4) << 3) + j;
  int ncol = cg * 16 + (lane & 15);
  P[li] = f2bf(W[k * dout + ncol]);
}

// ---------------- MFMA matmul: C[N,DOUT](bf16) = A[N,128] @ W ----------------
template <int DOUT, bool A_IS_F32>
__global__ __launch_bounds__(256) void mm_mfma_kernel(
    const void* __restrict__ Ap, const unsigned short* __restrict__ Wpack,
    unsigned short* __restrict__ C, int N) {
  constexpr int CG = DOUT / 16;
  constexpr int AS = 136;  // bf16 elems per LDS row (128 + 8 pad)
  __shared__ unsigned short As[64 * AS];
  const int t = threadIdx.x;
  const int lane = t & 63;
  const int w = t >> 6;
  const int row0 = blockIdx.x * 64;

  {  // stage A: thread t -> row t>>2, cols (t&3)*32 .. +32
    int r = t >> 2, c0 = (t & 3) * 32;
    int row = row0 + r;
    if (row >= N) row = N - 1;
    if (A_IS_F32) {
      const float* A = (const float*)Ap;
      const float* s = &A[(size_t)row * 128 + c0];
      unsigned short* d = &As[r * AS + c0];
#pragma unroll
      for (int i = 0; i < 32; i += 8) {
        float4 v0 = *(const float4*)(s + i);
        float4 v1 = *(const float4*)(s + i + 4);
        uint4 o;
        o.x = f2bf2(v0.x, v0.y); o.y = f2bf2(v0.z, v0.w);
        o.z = f2bf2(v1.x, v1.y); o.w = f2bf2(v1.z, v1.w);
        *(uint4*)(d + i) = o;
      }
    } else {
      const unsigned short* A = (const unsigned short*)Ap;
      const uint4* s = (const uint4*)&A[(size_t)row * 128 + c0];
      unsigned short* d = &As[r * AS + c0];
#pragma unroll
      for (int i = 0; i < 4; ++i) *(uint4*)(d + i * 8) = s[i];
    }
  }
  __syncthreads();

  const int m = lane & 15, q = lane >> 4;
  floatx4 acc[CG];
#pragma unroll
  for (int cg = 0; cg < CG; ++cg) acc[cg] = (floatx4){0.f, 0.f, 0.f, 0.f};

#pragma unroll
  for (int kc = 0; kc < 4; ++kc) {
    short8 a = *(const short8*)&As[(w * 16 + m) * AS + kc * 32 + q * 8];
#pragma unroll
    for (int cg = 0; cg < CG; ++cg) {
      short8 b = *(const short8*)&Wpack[((cg * 4 + kc) * 64 + lane) * 8];
      acc[cg] = __builtin_amdgcn_mfma_f32_16x16x32_bf16(a, b, acc[cg], 0, 0, 0);
    }
  }

  // C/D layout: col = lane&15 (=m), row = q*4 + reg
#pragma unroll
  for (int cg = 0; cg < CG; ++cg) {
#pragma unroll
    for (int r = 0; r < 4; ++r) {
      int row = row0 + w * 16 + q * 4 + r;
      if (row < N) C[(size_t)row * DOUT + cg * 16 + m] = f2bf(acc[cg][r]);
    }
  }
}

// ---------------- aggregation, D=128 bf16 rows ----------------
// wave/node; 4 groups x 16 lanes x 16B. Per-group broadcast int2 record
// load (16 lanes same addr -> one fetch). Unroll-2: group g handles edges
// e == g (mod 4); pair (e, e+4), step 8; tail handles the single leftover.
template <int MODE>
__global__ __launch_bounds__(256) void agg128_bf16_kernel(
    const unsigned short* __restrict__ h, const int* __restrict__ offs,
    const int2* __restrict__ esw, const float* __restrict__ bias,
    const unsigned short* __restrict__ x1in, unsigned short* __restrict__ out_main,
    unsigned short* __restrict__ out_x1, int n) {
  const int lane = threadIdx.x & 63;
  const int g = lane >> 4;
  const int fl = lane & 15;
  const int node = blockIdx.x * 4 + (threadIdx.x >> 6);
  if (node >= n) return;
  const int s0 = offs[node];
  const int s1 = offs[node + 1];
  float accA[8] = {0.f, 0.f, 0.f, 0.f, 0.f, 0.f, 0.f, 0.f};
  float accB[8] = {0.f, 0.f, 0.f, 0.f, 0.f, 0.f, 0.f, 0.f};
  int e = s0 + g;
  for (; e + 4 < s1; e += 8) {
    int2 rA = esw[e];
    int2 rB = esw[e + 4];
    float wA = __int_as_float(rA.y);
    float wB = __int_as_float(rB.y);
    uint4 vA = *(const uint4*)&h[(size_t)rA.x * 128 + fl * 8];
    uint4 vB = *(const uint4*)&h[(size_t)rB.x * 128 + fl * 8];
    accA[0] = fmaf(wA, bflo(vA.x), accA[0]);
    accA[1] = fmaf(wA, bfhi(vA.x), accA[1]);
    accA[2] = fmaf(wA, bflo(vA.y), accA[2]);
    accA[3] = fmaf(wA, bfhi(vA.y), accA[3]);
    accA[4] = fmaf(wA, bflo(vA.z), accA[4]);
    accA[5] = fmaf(wA, bfhi(vA.z), accA[5]);
    accA[6] = fmaf(wA, bflo(vA.w), accA[6]);
    accA[7] = fmaf(wA, bfhi(vA.w), accA[7]);
    accB[0] = fmaf(wB, bflo(vB.x), accB[0]);
    accB[1] = fmaf(wB, bfhi(vB.x), accB[1]);
    accB[2] = fmaf(wB, bflo(vB.y), accB[2]);
    accB[3] = fmaf(wB, bfhi(vB.y), accB[3]);
    accB[4] = fmaf(wB, bflo(vB.z), accB[4]);
    accB[5] = fmaf(wB, bfhi(vB.z), accB[5]);
    accB[6] = fmaf(wB, bflo(vB.w), accB[6]);
    accB[7] = fmaf(wB, bfhi(vB.w), accB[7]);
  }
  if (e < s1) {
    int2 rA = esw[e];
    float wA = __int_as_float(rA.y);
    uint4 vA = *(const uint4*)&h[(size_t)rA.x * 128 + fl * 8];
    accA[0] = fmaf(wA, bflo(vA.x), accA[0]);
    accA[1] = fmaf(wA, bfhi(vA.x), accA[1]);
    accA[2] = fmaf(wA, bflo(vA.y), accA[2]);
    accA[3] = fmaf(wA, bfhi(vA.y), accA[3]);
    accA[4] = fmaf(wA, bflo(vA.z), accA[4]);
    accA[5] = fmaf(wA, bfhi(vA.z), accA[5]);
    accA[6] = fmaf(wA, bflo(vA.w), accA[6]);
    accA[7] = fmaf(wA, bfhi(vA.w), accA[7]);
  }
  float acc[8];
#pragma unroll
  for (int i = 0; i < 8; ++i) acc[i] = accA[i] + accB[i];
#pragma unroll
  for (int msk = 16; msk < 64; msk <<= 1)
#pragma unroll
    for (int i = 0; i < 8; ++i) acc[i] += __shfl_xor(acc[i], msk, 64);
  if (g == 0) {
    float4 b0 = *(const float4*)&bias[fl * 8];
    float4 b1 = *(const float4*)&bias[fl * 8 + 4];
    float v[8];
    v[0] = acc[0] + b0.x; v[1] = acc[1] + b0.y; v[2] = acc[2] + b0.z;
    v[3] = acc[3] + b0.w; v[4] = acc[4] + b1.x; v[5] = acc[5] + b1.y;
    v[6] = acc[6] + b1.z; v[7] = acc[7] + b1.w;
    size_t o = (size_t)node * 128 + fl * 8;
    float hn[8];
    if (MODE == 0) {
      uint4 xo;
      xo.x = f2bf2(v[0], v[1]); xo.y = f2bf2(v[2], v[3]);
      xo.z = f2bf2(v[4], v[5]); xo.w = f2bf2(v[6], v[7]);
      *(uint4*)&out_x1[o] = xo;
#pragma unroll
      for (int i = 0; i < 8; ++i) hn[i] = v[i] + relu_f(v[i]);
    } else {
      uint4 x1v = *(const uint4*)&x1in[o];
      float xv[8] = {bflo(x1v.x), bfhi(x1v.x), bflo(x1v.y), bfhi(x1v.y),
                     bflo(x1v.z), bfhi(x1v.z), bflo(x1v.w), bfhi(x1v.w)};
#pragma unroll
      for (int i = 0; i < 8; ++i) hn[i] = xv[i] + relu_f(v[i]);
    }
    uint4 ho;
    ho.x = f2bf2(hn[0], hn[1]); ho.y = f2bf2(hn[2], hn[3]);
    ho.z = f2bf2(hn[4], hn[5]); ho.w = f2bf2(hn[6], hn[7]);
    *(uint4*)&out_main[o] = ho;
  }
}

// ---------------- aggregation, D=64 bf16 rows -> fp32 out ----------------
// 8 groups x 8 lanes x 16B; per-group broadcast int2 record load.
__global__ __launch_bounds__(256) void agg64_bf16_kernel(
    const unsigned short* __restrict__ h, const int* __restrict__ offs,
    const int2* __restrict__ esw, const float* __restrict__ bias,
    float* __restrict__ out, int n) {
  const int lane = threadIdx.x & 63;
  const int g = lane >> 3;
  const int fl = lane & 7;
  const int node = blockIdx.x * 4 + (threadIdx.x >> 6);
  if (node >= n) return;
  const int s0 = offs[node];
  const int s1 = offs[node + 1];
  float acc[8] = {0.f, 0.f, 0.f, 0.f, 0.f, 0.f, 0.f, 0.f};
  for (int e = s0 + g; e < s1; e += 8) {
    int2 r = esw[e];
    float wt = __int_as_float(r.y);
    uint4 v = *(const uint4*)&h[(size_t)r.x * 64 + fl * 8];
    acc[0] = fmaf(wt, bflo(v.x), acc[0]);
    acc[1] = fmaf(wt, bfhi(v.x), acc[1]);
    acc[2] = fmaf(wt, bflo(v.y), acc[2]);
    acc[3] = fmaf(wt, bfhi(v.y), acc[3]);
    acc[4] = fmaf(wt, bflo(v.z), acc[4]);
    acc[5] = fmaf(wt, bfhi(v.z), acc[5]);
    acc[6] = fmaf(wt, bflo(v.w), acc[6]);
    acc[7] = fmaf(wt, bfhi(v.w), acc[7]);
  }
#pragma unroll
  for (int msk = 8; msk < 64; msk <<= 1)
#pragma unroll
    for (int i = 0; i < 8; ++i) acc[i] += __shfl_xor(acc[i], msk, 64);
  if (g == 0) {
    float4 b0 = *(const float4*)&bias[fl * 8];
    float4 b1 = *(const float4*)&bias[fl * 8 + 4];
    float4 o0, o1;
    o0.x = acc[0] + b0.x; o0.y = acc[1] + b0.y;
    o0.z = acc[2] + b0.z; o0.w = acc[3] + b0.w;
    o1.x = acc[4] + b1.x; o1.y = acc[5] + b1.y;
    o1.z = acc[6] + b1.z; o1.w = acc[7] + b1.w;
    size_t o = (size_t)node * 64 + fl * 8;
    *(float4*)&out[o] = o0;
    *(float4*)&out[o + 4] = o1;
  }
}

extern "C" void kernel_launch(void* const* d_in, const int* in_sizes, int n_in,
                              void* d_out, int out_size, void* d_ws, size_t ws_size,
                              hipStream_t stream) {
  const float* x  = (const float*)d_in[0];
  const int*   ei = (const int*)d_in[1];
  const float* ew = (const float*)d_in[2];
  const float* W1 = (const float*)d_in[3];
  const float* b1 = (const float*)d_in[4];
  const float* W2 = (const float*)d_in[5];
  const float* b2 = (const float*)d_in[6];
  const float* W3 = (const float*)d_in[7];
  const float* b3 = (const float*)d_in[8];
  const int N = in_sizes[0] / 128;   // 50000
  const int E = in_sizes[2];         // 800000
  const int* src = ei;
  const int* dst = ei + E;

  char* p = (char*)d_ws;
  auto alloc = [&](size_t bytes) {
    void* q = (void*)p;
    p += (bytes + 511) & ~(size_t)511;
    return q;
  };
  int*   deg  = (int*)alloc((size_t)N * 4);
  int*   offs = (int*)alloc((size_t)(N + 1) * 4);
  int*   cur  = (int*)alloc((size_t)N * 4);
  int*   bsum = (int*)alloc(4096);
  int2*  esw  = (int2*)alloc((size_t)E * 8);
  unsigned short* hb  = (unsigned short*)alloc((size_t)N * 128 * 2);
  unsigned short* x1b = (unsigned short*)alloc((size_t)N * 128 * 2);
  unsigned short* cb  = (unsigned short*)alloc((size_t)N * 128 * 2);
  unsigned short* P1  = (unsigned short*)alloc(16384 * 2);
  unsigned short* P2  = (unsigned short*)alloc(16384 * 2);
  unsigned short* P3  = (unsigned short*)alloc(8192 * 2);
  (void)ws_size; (void)n_in; (void)out_size;

  const int nChunks = (N + 1023) / 1024;

  // CSR by destination
  hipMemsetAsync(deg, 0, (size_t)N * 4, stream);
  count_kernel<<<(E + 255) / 256, 256, 0, stream>>>(dst, deg, E);
  block_sum_kernel<<<nChunks, 256, 0, stream>>>(deg, bsum, N);
  scan_partials_kernel<<<1, 64, 0, stream>>>(bsum, nChunks);
  block_scan_kernel<<<nChunks, 1024, 0, stream>>>(deg, bsum, offs, cur, N);
  fill_kernel<<<(E + 255) / 256, 256, 0, stream>>>(src, dst, ew, cur, esw, E);

  // weight packing (frag order, bf16)
  pack_w_kernel<<<160, 256, 0, stream>>>(W1, W2, W3, P1, P2, P3);

  const int mmGrid = (N + 63) / 64;
  const int aggGrid = (N + 3) / 4;

  // Layer 1
  mm_mfma_kernel<128, true><<<mmGrid, 256, 0, stream>>>(x, P1, hb, N);
  agg128_bf16_kernel<0><<<aggGrid, 256, 0, stream>>>(hb, offs, esw, b1,
                                                     nullptr, cb, x1b, N);
  // Layer 2
  mm_mfma_kernel<128, false><<<mmGrid, 256, 0, stream>>>(cb, P2, hb, N);
  agg128_bf16_kernel<1><<<aggGrid, 256, 0, stream>>>(hb, offs, esw, b2,
                                                     x1b, cb, nullptr, N);
  // Layer 3
  mm_mfma_kernel<64, false><<<mmGrid, 256, 0, stream>>>(cb, P3, hb, N);
  agg64_bf16_kernel<<<aggGrid, 256, 0, stream>>>(hb, offs, esw, b3,
                                                 (float*)d_out, N);
}

// Round 6
// 268.245 us; speedup vs baseline: 2.2038x; 1.1444x over previous
//
#include <hip/hip_runtime.h>

// ---------------------------------------------------------------------------
// QGCN forward, round 6.
//  - CSR build rewritten as two-level LDS-staged counting sort:
//      bucket_count -> bucket_scan -> bin (bucket-sort, coalesced flush)
//      -> csr (per-bucket node-sort in LDS, coalesced final write + offs).
//    Round-5 fill_kernel did 800K random 8B scatters = 1 full 64B line
//    writeback per edge (WRITE_SIZE 52MB, 48us). All writes now coalesced.
//  - Record packing in tmp: x = src | (dst&511)<<23  (src < 2^23), y = ew.
//  - mm via MFMA 16x16x32 bf16; agg reads bf16 rows (unchanged, round 5).
// ---------------------------------------------------------------------------

typedef __attribute__((ext_vector_type(8))) short short8;
typedef __attribute__((ext_vector_type(4))) float floatx4;

constexpr int BSHIFT = 9;    // 512 nodes per bucket
constexpr int MAXB = 128;    // max buckets (N <= 65536)
constexpr int TILE = 4096;   // edges per bin block
constexpr int RCAP = 12288;  // csr LDS record cap (mean ~8163, sigma ~90)

__device__ __forceinline__ float relu_f(float v) { return v > 0.f ? v : 0.f; }

__device__ __forceinline__ unsigned short f2bf(float f) {
  union { float f; unsigned int i; } v; v.f = f;
  unsigned int r = v.i + 0x7fffu + ((v.i >> 16) & 1u);  // RNE
  return (unsigned short)(r >> 16);
}
__device__ __forceinline__ unsigned int f2bf2(float lo, float hi) {
  return (unsigned int)f2bf(lo) | ((unsigned int)f2bf(hi) << 16);
}
__device__ __forceinline__ float bflo(unsigned int u) {
  union { unsigned int i; float f; } v; v.i = u << 16; return v.f;
}
__device__ __forceinline__ float bfhi(unsigned int u) {
  union { unsigned int i; float f; } v; v.i = u & 0xffff0000u; return v.f;
}

// ---------------- CSR build: two-level counting sort ----------------
__global__ __launch_bounds__(256) void bucket_count_kernel(
    const int* __restrict__ dst, int* __restrict__ bcount, int E, int nb) {
  __shared__ int h[MAXB];
  int t = threadIdx.x;
  for (int i = t; i < MAXB; i += 256) h[i] = 0;
  __syncthreads();
  for (int e = blockIdx.x * 256 + t; e < E; e += gridDim.x * 256)
    atomicAdd(&h[dst[e] >> BSHIFT], 1);
  __syncthreads();
  for (int i = t; i < nb; i += 256)
    if (h[i]) atomicAdd(&bcount[i], h[i]);
}

__global__ __launch_bounds__(MAXB) void bucket_scan_kernel(
    const int* __restrict__ bcount, int* __restrict__ bstart,
    int* __restrict__ bcur, int* __restrict__ offs, int N, int E, int nb) {
  __shared__ int buf[MAXB];
  int t = threadIdx.x;
  int c = (t < nb) ? bcount[t] : 0;
  buf[t] = c;
  __syncthreads();
#pragma unroll
  for (int off = 1; off < MAXB; off <<= 1) {
    int y = (t >= off) ? buf[t - off] : 0;
    __syncthreads();
    buf[t] += y;
    __syncthreads();
  }
  if (t < nb) {
    int ex = buf[t] - c;
    bstart[t] = ex;
    bcur[t] = ex;
  }
  if (t == 0) { bstart[nb] = E; offs[N] = E; }
}

// Bucket-sort a 4096-edge tile in LDS, reserve global ranges, flush coalesced.
__global__ __launch_bounds__(256) void bin_kernel(
    const int* __restrict__ src, const int* __restrict__ dst,
    const float* __restrict__ ew, int* __restrict__ bcur,
    int2* __restrict__ tmp, int E, int nb) {
  __shared__ int hist[MAXB];
  __shared__ int segStart[MAXB];
  __shared__ int gbase[MAXB];
  __shared__ int cursor[MAXB];
  __shared__ int2 srt[TILE];
  __shared__ unsigned char bos[TILE];
  const int t = threadIdx.x;
  const int base = blockIdx.x * TILE;
  int m = E - base;
  if (m > TILE) m = TILE;
  for (int i = t; i < MAXB; i += 256) { hist[i] = 0; cursor[i] = 0; }
  __syncthreads();
  for (int i = t; i < m; i += 256)
    atomicAdd(&hist[dst[base + i] >> BSHIFT], 1);
  __syncthreads();
  if (t < MAXB) segStart[t] = hist[t];
  __syncthreads();
#pragma unroll
  for (int off = 1; off < MAXB; off <<= 1) {
    int y = (t < MAXB && t >= off) ? segStart[t - off] : 0;
    __syncthreads();
    if (t < MAXB) segStart[t] += y;
    __syncthreads();
  }
  if (t < MAXB) segStart[t] -= hist[t];  // exclusive
  __syncthreads();
  if (t < nb) {
    int c = hist[t];
    gbase[t] = c ? atomicAdd(&bcur[t], c) : 0;
  }
  __syncthreads();
  for (int i = t; i < m; i += 256) {
    int d = dst[base + i];
    int b = d >> BSHIFT;
    int r = atomicAdd(&cursor[b], 1);
    int slot = segStart[b] + r;
    int2 rec;
    rec.x = src[base + i] | ((d & 511) << 23);
    rec.y = __float_as_int(ew[base + i]);
    srt[slot] = rec;
    bos[slot] = (unsigned char)b;
  }
  __syncthreads();
  for (int j = t; j < m; j += 256) {
    int b = bos[j];
    tmp[gbase[b] + (j - segStart[b])] = srt[j];
  }
}

// Per-bucket: node-histogram + scan -> offs; node-sort records via LDS,
// flush final CSR coalesced.
__global__ __launch_bounds__(256) void csr_kernel(
    const int2* __restrict__ tmp, const int* __restrict__ bstart,
    int* __restrict__ offs, int2* __restrict__ esw, int N) {
  __shared__ int nodeStart[512];
  __shared__ int cur[512];
  __shared__ int2 outb[RCAP];
  const int b = blockIdx.x;
  const int t = threadIdx.x;
  const int gs = bstart[b], ge = bstart[b + 1];
  const int cnt = ge - gs;
  for (int i = t; i < 512; i += 256) { nodeStart[i] = 0; cur[i] = 0; }
  __syncthreads();
  for (int i = t; i < cnt; i += 256)
    atomicAdd(&nodeStart[((unsigned)tmp[gs + i].x) >> 23], 1);
  __syncthreads();
  int c1 = nodeStart[t], c2 = nodeStart[t + 256];
#pragma unroll
  for (int off = 1; off < 512; off <<= 1) {
    int y1 = (t >= off) ? nodeStart[t - off] : 0;
    int y2 = (t + 256 >= off) ? nodeStart[t + 256 - off] : 0;
    __syncthreads();
    nodeStart[t] += y1;
    nodeStart[t + 256] += y2;
    __syncthreads();
  }
  nodeStart[t] -= c1;          // exclusive
  nodeStart[t + 256] -= c2;
  __syncthreads();
  {
    int g1 = (b << BSHIFT) + t;
    int g2 = g1 + 256;
    if (g1 < N) offs[g1] = gs + nodeStart[t];
    if (g2 < N) offs[g2] = gs + nodeStart[t + 256];
  }
  const bool fast = (cnt <= RCAP);
  for (int i = t; i < cnt; i += 256) {
    int2 r = tmp[gs + i];
    int node = ((unsigned)r.x) >> 23;
    int pos = nodeStart[node] + atomicAdd(&cur[node], 1);
    int2 cle;
    cle.x = r.x & 0x7FFFFF;
    cle.y = r.y;
    if (fast) outb[pos] = cle;
    else esw[gs + pos] = cle;  // improbable overflow fallback
  }
  __syncthreads();
  if (fast)
    for (int i = t; i < cnt; i += 256) esw[gs + i] = outb[i];
}

// ---------------- weight pack: W[k][n] fp32 -> frag-order bf16 --------------
__global__ __launch_bounds__(256) void pack_w_kernel(
    const float* __restrict__ W1, const float* __restrict__ W2,
    const float* __restrict__ W3, unsigned short* __restrict__ P1,
    unsigned short* __restrict__ P2, unsigned short* __restrict__ P3) {
  int idx = blockIdx.x * 256 + threadIdx.x;  // 40960 total
  const float* W; unsigned short* P; int dout, li;
  if (idx < 16384)      { W = W1; P = P1; dout = 128; li = idx; }
  else if (idx < 32768) { W = W2; P = P2; dout = 128; li = idx - 16384; }
  else if (idx < 40960) { W = W3; P = P3; dout = 64;  li = idx - 32768; }
  else return;
  int j = li & 7, lane = (li >> 3) & 63, kc = (li >> 9) & 3, cg = li >> 11;
  int k = kc * 32 + ((lane >> 4) << 3) + j;
  int ncol = cg * 16 + (lane & 15);
  P[li] = f2bf(W[k * dout + ncol]);
}

// ---------------- MFMA matmul: C[N,DOUT](bf16) = A[N,128] @ W ----------------
template <int DOUT, bool A_IS_F32>
__global__ __launch_bounds__(256) void mm_mfma_kernel(
    const void* __restrict__ Ap, const unsigned short* __restrict__ Wpack,
    unsigned short* __restrict__ C, int N) {
  constexpr int CG = DOUT / 16;
  constexpr int AS = 136;  // bf16 elems per LDS row (128 + 8 pad)
  __shared__ unsigned short As[64 * AS];
  const int t = threadIdx.x;
  const int lane = t & 63;
  const int w = t >> 6;
  const int row0 = blockIdx.x * 64;

  {  // stage A: thread t -> row t>>2, cols (t&3)*32 .. +32
    int r = t >> 2, c0 = (t & 3) * 32;
    int row = row0 + r;
    if (row >= N) row = N - 1;
    if (A_IS_F32) {
      const float* A = (const float*)Ap;
      const float* s = &A[(size_t)row * 128 + c0];
      unsigned short* d = &As[r * AS + c0];
#pragma unroll
      for (int i = 0; i < 32; i += 8) {
        float4 v0 = *(const float4*)(s + i);
        float4 v1 = *(const float4*)(s + i + 4);
        uint4 o;
        o.x = f2bf2(v0.x, v0.y); o.y = f2bf2(v0.z, v0.w);
        o.z = f2bf2(v1.x, v1.y); o.w = f2bf2(v1.z, v1.w);
        *(uint4*)(d + i) = o;
      }
    } else {
      const unsigned short* A = (const unsigned short*)Ap;
      const uint4* s = (const uint4*)&A[(size_t)row * 128 + c0];
      unsigned short* d = &As[r * AS + c0];
#pragma unroll
      for (int i = 0; i < 4; ++i) *(uint4*)(d + i * 8) = s[i];
    }
  }
  __syncthreads();

  const int m = lane & 15, q = lane >> 4;
  floatx4 acc[CG];
#pragma unroll
  for (int cg = 0; cg < CG; ++cg) acc[cg] = (floatx4){0.f, 0.f, 0.f, 0.f};

#pragma unroll
  for (int kc = 0; kc < 4; ++kc) {
    short8 a = *(const short8*)&As[(w * 16 + m) * AS + kc * 32 + q * 8];
#pragma unroll
    for (int cg = 0; cg < CG; ++cg) {
      short8 b = *(const short8*)&Wpack[((cg * 4 + kc) * 64 + lane) * 8];
      acc[cg] = __builtin_amdgcn_mfma_f32_16x16x32_bf16(a, b, acc[cg], 0, 0, 0);
    }
  }

  // C/D layout: col = lane&15 (=m), row = q*4 + reg
#pragma unroll
  for (int cg = 0; cg < CG; ++cg) {
#pragma unroll
    for (int r = 0; r < 4; ++r) {
      int row = row0 + w * 16 + q * 4 + r;
      if (row < N) C[(size_t)row * DOUT + cg * 16 + m] = f2bf(acc[cg][r]);
    }
  }
}

// ---------------- aggregation, D=128 bf16 rows ----------------
template <int MODE>
__global__ __launch_bounds__(256) void agg128_bf16_kernel(
    const unsigned short* __restrict__ h, const int* __restrict__ offs,
    const int2* __restrict__ esw, const float* __restrict__ bias,
    const unsigned short* __restrict__ x1in, unsigned short* __restrict__ out_main,
    unsigned short* __restrict__ out_x1, int n) {
  const int lane = threadIdx.x & 63;
  const int g = lane >> 4;
  const int fl = lane & 15;
  const int node = blockIdx.x * 4 + (threadIdx.x >> 6);
  if (node >= n) return;
  const int s0 = offs[node];
  const int s1 = offs[node + 1];
  float accA[8] = {0.f, 0.f, 0.f, 0.f, 0.f, 0.f, 0.f, 0.f};
  float accB[8] = {0.f, 0.f, 0.f, 0.f, 0.f, 0.f, 0.f, 0.f};
  int e = s0 + g;
  for (; e + 4 < s1; e += 8) {
    int2 rA = esw[e];
    int2 rB = esw[e + 4];
    float wA = __int_as_float(rA.y);
    float wB = __int_as_float(rB.y);
    uint4 vA = *(const uint4*)&h[(size_t)rA.x * 128 + fl * 8];
    uint4 vB = *(const uint4*)&h[(size_t)rB.x * 128 + fl * 8];
    accA[0] = fmaf(wA, bflo(vA.x), accA[0]);
    accA[1] = fmaf(wA, bfhi(vA.x), accA[1]);
    accA[2] = fmaf(wA, bflo(vA.y), accA[2]);
    accA[3] = fmaf(wA, bfhi(vA.y), accA[3]);
    accA[4] = fmaf(wA, bflo(vA.z), accA[4]);
    accA[5] = fmaf(wA, bfhi(vA.z), accA[5]);
    accA[6] = fmaf(wA, bflo(vA.w), accA[6]);
    accA[7] = fmaf(wA, bfhi(vA.w), accA[7]);
    accB[0] = fmaf(wB, bflo(vB.x), accB[0]);
    accB[1] = fmaf(wB, bfhi(vB.x), accB[1]);
    accB[2] = fmaf(wB, bflo(vB.y), accB[2]);
    accB[3] = fmaf(wB, bfhi(vB.y), accB[3]);
    accB[4] = fmaf(wB, bflo(vB.z), accB[4]);
    accB[5] = fmaf(wB, bfhi(vB.z), accB[5]);
    accB[6] = fmaf(wB, bflo(vB.w), accB[6]);
    accB[7] = fmaf(wB, bfhi(vB.w), accB[7]);
  }
  if (e < s1) {
    int2 rA = esw[e];
    float wA = __int_as_float(rA.y);
    uint4 vA = *(const uint4*)&h[(size_t)rA.x * 128 + fl * 8];
    accA[0] = fmaf(wA, bflo(vA.x), accA[0]);
    accA[1] = fmaf(wA, bfhi(vA.x), accA[1]);
    accA[2] = fmaf(wA, bflo(vA.y), accA[2]);
    accA[3] = fmaf(wA, bfhi(vA.y), accA[3]);
    accA[4] = fmaf(wA, bflo(vA.z), accA[4]);
    accA[5] = fmaf(wA, bfhi(vA.z), accA[5]);
    accA[6] = fmaf(wA, bflo(vA.w), accA[6]);
    accA[7] = fmaf(wA, bfhi(vA.w), accA[7]);
  }
  float acc[8];
#pragma unroll
  for (int i = 0; i < 8; ++i) acc[i] = accA[i] + accB[i];
#pragma unroll
  for (int msk = 16; msk < 64; msk <<= 1)
#pragma unroll
    for (int i = 0; i < 8; ++i) acc[i] += __shfl_xor(acc[i], msk, 64);
  if (g == 0) {
    float4 b0 = *(const float4*)&bias[fl * 8];
    float4 b1 = *(const float4*)&bias[fl * 8 + 4];
    float v[8];
    v[0] = acc[0] + b0.x; v[1] = acc[1] + b0.y; v[2] = acc[2] + b0.z;
    v[3] = acc[3] + b0.w; v[4] = acc[4] + b1.x; v[5] = acc[5] + b1.y;
    v[6] = acc[6] + b1.z; v[7] = acc[7] + b1.w;
    size_t o = (size_t)node * 128 + fl * 8;
    float hn[8];
    if (MODE == 0) {
      uint4 xo;
      xo.x = f2bf2(v[0], v[1]); xo.y = f2bf2(v[2], v[3]);
      xo.z = f2bf2(v[4], v[5]); xo.w = f2bf2(v[6], v[7]);
      *(uint4*)&out_x1[o] = xo;
#pragma unroll
      for (int i = 0; i < 8; ++i) hn[i] = v[i] + relu_f(v[i]);
    } else {
      uint4 x1v = *(const uint4*)&x1in[o];
      float xv[8] = {bflo(x1v.x), bfhi(x1v.x), bflo(x1v.y), bfhi(x1v.y),
                     bflo(x1v.z), bfhi(x1v.z), bflo(x1v.w), bfhi(x1v.w)};
#pragma unroll
      for (int i = 0; i < 8; ++i) hn[i] = xv[i] + relu_f(v[i]);
    }
    uint4 ho;
    ho.x = f2bf2(hn[0], hn[1]); ho.y = f2bf2(hn[2], hn[3]);
    ho.z = f2bf2(hn[4], hn[5]); ho.w = f2bf2(hn[6], hn[7]);
    *(uint4*)&out_main[o] = ho;
  }
}

// ---------------- aggregation, D=64 bf16 rows -> fp32 out ----------------
__global__ __launch_bounds__(256) void agg64_bf16_kernel(
    const unsigned short* __restrict__ h, const int* __restrict__ offs,
    const int2* __restrict__ esw, const float* __restrict__ bias,
    float* __restrict__ out, int n) {
  const int lane = threadIdx.x & 63;
  const int g = lane >> 3;
  const int fl = lane & 7;
  const int node = blockIdx.x * 4 + (threadIdx.x >> 6);
  if (node >= n) return;
  const int s0 = offs[node];
  const int s1 = offs[node + 1];
  float acc[8] = {0.f, 0.f, 0.f, 0.f, 0.f, 0.f, 0.f, 0.f};
  for (int e = s0 + g; e < s1; e += 8) {
    int2 r = esw[e];
    float wt = __int_as_float(r.y);
    uint4 v = *(const uint4*)&h[(size_t)r.x * 64 + fl * 8];
    acc[0] = fmaf(wt, bflo(v.x), acc[0]);
    acc[1] = fmaf(wt, bfhi(v.x), acc[1]);
    acc[2] = fmaf(wt, bflo(v.y), acc[2]);
    acc[3] = fmaf(wt, bfhi(v.y), acc[3]);
    acc[4] = fmaf(wt, bflo(v.z), acc[4]);
    acc[5] = fmaf(wt, bfhi(v.z), acc[5]);
    acc[6] = fmaf(wt, bflo(v.w), acc[6]);
    acc[7] = fmaf(wt, bfhi(v.w), acc[7]);
  }
#pragma unroll
  for (int msk = 8; msk < 64; msk <<= 1)
#pragma unroll
    for (int i = 0; i < 8; ++i) acc[i] += __shfl_xor(acc[i], msk, 64);
  if (g == 0) {
    float4 b0 = *(const float4*)&bias[fl * 8];
    float4 b1 = *(const float4*)&bias[fl * 8 + 4];
    float4 o0, o1;
    o0.x = acc[0] + b0.x; o0.y = acc[1] + b0.y;
    o0.z = acc[2] + b0.z; o0.w = acc[3] + b0.w;
    o1.x = acc[4] + b1.x; o1.y = acc[5] + b1.y;
    o1.z = acc[6] + b1.z; o1.w = acc[7] + b1.w;
    size_t o = (size_t)node * 64 + fl * 8;
    *(float4*)&out[o] = o0;
    *(float4*)&out[o + 4] = o1;
  }
}

extern "C" void kernel_launch(void* const* d_in, const int* in_sizes, int n_in,
                              void* d_out, int out_size, void* d_ws, size_t ws_size,
                              hipStream_t stream) {
  const float* x  = (const float*)d_in[0];
  const int*   ei = (const int*)d_in[1];
  const float* ew = (const float*)d_in[2];
  const float* W1 = (const float*)d_in[3];
  const float* b1 = (const float*)d_in[4];
  const float* W2 = (const float*)d_in[5];
  const float* b2 = (const float*)d_in[6];
  const float* W3 = (const float*)d_in[7];
  const float* b3 = (const float*)d_in[8];
  const int N = in_sizes[0] / 128;   // 50000
  const int E = in_sizes[2];         // 800000
  const int* src = ei;
  const int* dst = ei + E;
  const int nb = (N + 511) >> BSHIFT;  // 98

  char* p = (char*)d_ws;
  auto alloc = [&](size_t bytes) {
    void* q = (void*)p;
    p += (bytes + 511) & ~(size_t)511;
    return q;
  };
  int*   offs   = (int*)alloc((size_t)(N + 1) * 4);
  int*   bcount = (int*)alloc(MAXB * 4);
  int*   bstart = (int*)alloc((MAXB + 1) * 4);
  int*   bcur   = (int*)alloc(MAXB * 4);
  int2*  tmp    = (int2*)alloc((size_t)E * 8);
  int2*  esw    = (int2*)alloc((size_t)E * 8);
  unsigned short* hb  = (unsigned short*)alloc((size_t)N * 128 * 2);
  unsigned short* x1b = (unsigned short*)alloc((size_t)N * 128 * 2);
  unsigned short* cb  = (unsigned short*)alloc((size_t)N * 128 * 2);
  unsigned short* P1  = (unsigned short*)alloc(16384 * 2);
  unsigned short* P2  = (unsigned short*)alloc(16384 * 2);
  unsigned short* P3  = (unsigned short*)alloc(8192 * 2);
  (void)ws_size; (void)n_in; (void)out_size;

  // CSR by destination: two-level counting sort
  hipMemsetAsync(bcount, 0, MAXB * 4, stream);
  bucket_count_kernel<<<512, 256, 0, stream>>>(dst, bcount, E, nb);
  bucket_scan_kernel<<<1, MAXB, 0, stream>>>(bcount, bstart, bcur, offs, N, E, nb);
  bin_kernel<<<(E + TILE - 1) / TILE, 256, 0, stream>>>(src, dst, ew, bcur, tmp,
                                                        E, nb);
  csr_kernel<<<nb, 256, 0, stream>>>(tmp, bstart, offs, esw, N);

  // weight packing (frag order, bf16)
  pack_w_kernel<<<160, 256, 0, stream>>>(W1, W2, W3, P1, P2, P3);

  const int mmGrid = (N + 63) / 64;
  const int aggGrid = (N + 3) / 4;

  // Layer 1
  mm_mfma_kernel<128, true><<<mmGrid, 256, 0, stream>>>(x, P1, hb, N);
  agg128_bf16_kernel<0><<<aggGrid, 256, 0, stream>>>(hb, offs, esw, b1,
                                                     nullptr, cb, x1b, N);
  // Layer 2
  mm_mfma_kernel<128, false><<<mmGrid, 256, 0, stream>>>(cb, P2, hb, N);
  agg128_bf16_kernel<1><<<aggGrid, 256, 0, stream>>>(hb, offs, esw, b2,
                                                     x1b, cb, nullptr, N);
  // Layer 3
  mm_mfma_kernel<64, false><<<mmGrid, 256, 0, stream>>>(cb, P3, hb, N);
  agg64_bf16_kernel<<<aggGrid, 256, 0, stream>>>(hb, offs, esw, b3,
                                                 (float*)d_out, N);
}

// Round 7
// 255.625 us; speedup vs baseline: 2.3126x; 1.0494x over previous
//
#include <hip/hip_runtime.h>

// ---------------------------------------------------------------------------
// QGCN forward, round 7.
//  - BSHIFT 9->8: csr_kernel 98 -> 196 blocks (was the CU-underutilized step).
//  - Fused launches: [bucket_count + pack_w], [bin + mm1] (independent work
//    overlapped inside one dispatch; serial chain 12 -> 9 kernels).
//  - agg unroll-4 (agg64 unroll-2): whole per-group edge list in flight.
//  - mm via MFMA 16x16x32 bf16; CSR two-level counting sort (round 6).
// ---------------------------------------------------------------------------

typedef __attribute__((ext_vector_type(8))) short short8;
typedef __attribute__((ext_vector_type(4))) float floatx4;

constexpr int BSHIFT = 8;    // 256 nodes per bucket
constexpr int MAXB = 256;    // max buckets (N <= 65536)
constexpr int TILE = 4096;   // edges per bin block
constexpr int RCAP = 5120;   // csr LDS record cap (mean ~4082, sigma ~64)

__device__ __forceinline__ float relu_f(float v) { return v > 0.f ? v : 0.f; }

__device__ __forceinline__ unsigned short f2bf(float f) {
  union { float f; unsigned int i; } v; v.f = f;
  unsigned int r = v.i + 0x7fffu + ((v.i >> 16) & 1u);  // RNE
  return (unsigned short)(r >> 16);
}
__device__ __forceinline__ unsigned int f2bf2(float lo, float hi) {
  return (unsigned int)f2bf(lo) | ((unsigned int)f2bf(hi) << 16);
}
__device__ __forceinline__ float bflo(unsigned int u) {
  union { unsigned int i; float f; } v; v.i = u << 16; return v.f;
}
__device__ __forceinline__ float bfhi(unsigned int u) {
  union { unsigned int i; float f; } v; v.i = u & 0xffff0000u; return v.f;
}

// ---------------- K1: fused bucket histogram + weight pack ----------------
__global__ __launch_bounds__(256) void count_pack_kernel(
    const int* __restrict__ dst, int* __restrict__ bcount, int E, int nb,
    const float* __restrict__ W1, const float* __restrict__ W2,
    const float* __restrict__ W3, unsigned short* __restrict__ P1,
    unsigned short* __restrict__ P2, unsigned short* __restrict__ P3) {
  const int t = threadIdx.x;
  if (blockIdx.x < 256) {
    __shared__ int h[MAXB];
    for (int i = t; i < MAXB; i += 256) h[i] = 0;
    __syncthreads();
    for (int e = blockIdx.x * 256 + t; e < E; e += 256 * 256)
      atomicAdd(&h[dst[e] >> BSHIFT], 1);
    __syncthreads();
    for (int i = t; i < nb; i += 256)
      if (h[i]) atomicAdd(&bcount[i], h[i]);
  } else {
    int idx = (blockIdx.x - 256) * 256 + t;  // 40960 total
    const float* W; unsigned short* P; int dout, li;
    if (idx < 16384)      { W = W1; P = P1; dout = 128; li = idx; }
    else if (idx < 32768) { W = W2; P = P2; dout = 128; li = idx - 16384; }
    else if (idx < 40960) { W = W3; P = P3; dout = 64;  li = idx - 32768; }
    else return;
    int j = li & 7, lane = (li >> 3) & 63, kc = (li >> 9) & 3, cg = li >> 11;
    int k = kc * 32 + ((lane >> 4) << 3) + j;
    int ncol = cg * 16 + (lane & 15);
    P[li] = f2bf(W[k * dout + ncol]);
  }
}

// ---------------- K2: bucket exclusive scan ----------------
__global__ __launch_bounds__(256) void bucket_scan_kernel(
    const int* __restrict__ bcount, int* __restrict__ bstart,
    int* __restrict__ bcur, int* __restrict__ offs, int N, int E, int nb) {
  __shared__ int buf[MAXB];
  int t = threadIdx.x;
  int c = (t < nb) ? bcount[t] : 0;
  buf[t] = c;
  __syncthreads();
#pragma unroll
  for (int off = 1; off < MAXB; off <<= 1) {
    int y = (t >= off) ? buf[t - off] : 0;
    __syncthreads();
    buf[t] += y;
    __syncthreads();
  }
  if (t < nb) {
    int ex = buf[t] - c;
    bstart[t] = ex;
    bcur[t] = ex;
  }
  if (t == 0) { bstart[nb] = E; offs[N] = E; }
}

// ---------------- bin body: bucket-sort a 4096-edge tile in LDS ----------
__device__ __forceinline__ void bin_body(
    const int* __restrict__ src, const int* __restrict__ dst,
    const float* __restrict__ ew, int* __restrict__ bcur,
    int2* __restrict__ tmp, int E, int nb, int blk, char* smem) {
  int* hist = (int*)smem;                      // 256
  int* segStart = hist + 256;                  // 256
  int* gbase = segStart + 256;                 // 256
  int* cursor = gbase + 256;                   // 256  (ints end at 4KB)
  int2* srt = (int2*)(smem + 4096);            // 4096 recs, 32KB
  unsigned char* bos = (unsigned char*)(smem + 4096 + 32768);  // 4096
  const int t = threadIdx.x;
  const int base = blk * TILE;
  int m = E - base;
  if (m > TILE) m = TILE;
  hist[t] = 0; cursor[t] = 0;
  __syncthreads();
  for (int i = t; i < m; i += 256)
    atomicAdd(&hist[dst[base + i] >> BSHIFT], 1);
  __syncthreads();
  segStart[t] = hist[t];
  __syncthreads();
#pragma unroll
  for (int off = 1; off < MAXB; off <<= 1) {
    int y = (t >= off) ? segStart[t - off] : 0;
    __syncthreads();
    segStart[t] += y;
    __syncthreads();
  }
  segStart[t] -= hist[t];  // exclusive
  __syncthreads();
  if (t < nb) {
    int c = hist[t];
    gbase[t] = c ? atomicAdd(&bcur[t], c) : 0;
  }
  __syncthreads();
  for (int i = t; i < m; i += 256) {
    int d = dst[base + i];
    int b = d >> BSHIFT;
    int r = atomicAdd(&cursor[b], 1);
    int slot = segStart[b] + r;
    int2 rec;
    rec.x = src[base + i] | ((d & 255) << 23);
    rec.y = __float_as_int(ew[base + i]);
    srt[slot] = rec;
    bos[slot] = (unsigned char)b;
  }
  __syncthreads();
  for (int j = t; j < m; j += 256) {
    int b = bos[j];
    tmp[gbase[b] + (j - segStart[b])] = srt[j];
  }
}

// ---------------- mm body: C[N,DOUT](bf16) = A[N,128] @ Wpack --------------
template <int DOUT, bool A_IS_F32>
__device__ __forceinline__ void mm_body(
    const void* __restrict__ Ap, const unsigned short* __restrict__ Wpack,
    unsigned short* __restrict__ C, int N, int blk, char* smem) {
  constexpr int CG = DOUT / 16;
  constexpr int AS = 136;  // bf16 elems per LDS row (128 + 8 pad)
  unsigned short* As = (unsigned short*)smem;
  const int t = threadIdx.x;
  const int lane = t & 63;
  const int w = t >> 6;
  const int row0 = blk * 64;

  {  // stage A: thread t -> row t>>2, cols (t&3)*32 .. +32
    int r = t >> 2, c0 = (t & 3) * 32;
    int row = row0 + r;
    if (row >= N) row = N - 1;
    if (A_IS_F32) {
      const float* A = (const float*)Ap;
      const float* s = &A[(size_t)row * 128 + c0];
      unsigned short* d = &As[r * AS + c0];
#pragma unroll
      for (int i = 0; i < 32; i += 8) {
        float4 v0 = *(const float4*)(s + i);
        float4 v1 = *(const float4*)(s + i + 4);
        uint4 o;
        o.x = f2bf2(v0.x, v0.y); o.y = f2bf2(v0.z, v0.w);
        o.z = f2bf2(v1.x, v1.y); o.w = f2bf2(v1.z, v1.w);
        *(uint4*)(d + i) = o;
      }
    } else {
      const unsigned short* A = (const unsigned short*)Ap;
      const uint4* s = (const uint4*)&A[(size_t)row * 128 + c0];
      unsigned short* d = &As[r * AS + c0];
#pragma unroll
      for (int i = 0; i < 4; ++i) *(uint4*)(d + i * 8) = s[i];
    }
  }
  __syncthreads();

  const int m = lane & 15, q = lane >> 4;
  floatx4 acc[CG];
#pragma unroll
  for (int cg = 0; cg < CG; ++cg) acc[cg] = (floatx4){0.f, 0.f, 0.f, 0.f};

#pragma unroll
  for (int kc = 0; kc < 4; ++kc) {
    short8 a = *(const short8*)&As[(w * 16 + m) * AS + kc * 32 + q * 8];
#pragma unroll
    for (int cg = 0; cg < CG; ++cg) {
      short8 b = *(const short8*)&Wpack[((cg * 4 + kc) * 64 + lane) * 8];
      acc[cg] = __builtin_amdgcn_mfma_f32_16x16x32_bf16(a, b, acc[cg], 0, 0, 0);
    }
  }

  // C/D layout: col = lane&15 (=m), row = q*4 + reg
#pragma unroll
  for (int cg = 0; cg < CG; ++cg) {
#pragma unroll
    for (int r = 0; r < 4; ++r) {
      int row = row0 + w * 16 + q * 4 + r;
      if (row < N) C[(size_t)row * DOUT + cg * 16 + m] = f2bf(acc[cg][r]);
    }
  }
}

// ---------------- K3: fused bin + layer-1 mm (independent work) ------------
__global__ __launch_bounds__(256) void bin_mm1_kernel(
    const int* __restrict__ src, const int* __restrict__ dst,
    const float* __restrict__ ew, int* __restrict__ bcur,
    int2* __restrict__ tmp, int E, int nb, int binBlocks,
    const float* __restrict__ x, const unsigned short* __restrict__ P1,
    unsigned short* __restrict__ hb, int N) {
  extern __shared__ char smem[];
  if ((int)blockIdx.x < binBlocks)
    bin_body(src, dst, ew, bcur, tmp, E, nb, blockIdx.x, smem);
  else
    mm_body<128, true>(x, P1, hb, N, blockIdx.x - binBlocks, smem);
}

// ---------------- standalone mm kernels (layers 2,3) ----------------
template <int DOUT, bool A_IS_F32>
__global__ __launch_bounds__(256) void mm_mfma_kernel(
    const void* __restrict__ Ap, const unsigned short* __restrict__ Wpack,
    unsigned short* __restrict__ C, int N) {
  extern __shared__ char smem[];
  mm_body<DOUT, A_IS_F32>(Ap, Wpack, C, N, blockIdx.x, smem);
}

// ---------------- K4: per-bucket node sort -> offs + esw ----------------
__global__ __launch_bounds__(256) void csr_kernel(
    const int2* __restrict__ tmp, const int* __restrict__ bstart,
    int* __restrict__ offs, int2* __restrict__ esw, int N) {
  __shared__ int nodeStart[256];
  __shared__ int cur[256];
  __shared__ int2 outb[RCAP];
  const int b = blockIdx.x;
  const int t = threadIdx.x;
  const int gs = bstart[b], ge = bstart[b + 1];
  const int cnt = ge - gs;
  nodeStart[t] = 0; cur[t] = 0;
  __syncthreads();
  for (int i = t; i < cnt; i += 256)
    atomicAdd(&nodeStart[((unsigned)tmp[gs + i].x) >> 23], 1);
  __syncthreads();
  int c = nodeStart[t];
#pragma unroll
  for (int off = 1; off < 256; off <<= 1) {
    int y = (t >= off) ? nodeStart[t - off] : 0;
    __syncthreads();
    nodeStart[t] += y;
    __syncthreads();
  }
  nodeStart[t] -= c;  // exclusive
  __syncthreads();
  {
    int gnode = (b << BSHIFT) + t;
    if (gnode < N) offs[gnode] = gs + nodeStart[t];
  }
  const bool fast = (cnt <= RCAP);
  for (int i = t; i < cnt; i += 256) {
    int2 r = tmp[gs + i];
    int node = ((unsigned)r.x) >> 23;
    int pos = nodeStart[node] + atomicAdd(&cur[node], 1);
    int2 cle;
    cle.x = r.x & 0x7FFFFF;
    cle.y = r.y;
    if (fast) outb[pos] = cle;
    else esw[gs + pos] = cle;  // improbable overflow fallback
  }
  __syncthreads();
  if (fast)
    for (int i = t; i < cnt; i += 256) esw[gs + i] = outb[i];
}

// ---------------- aggregation, D=128 bf16 rows, unroll-4 ----------------
#define ACC8(acc, wt, v)                          \
  acc[0] = fmaf(wt, bflo(v.x), acc[0]);           \
  acc[1] = fmaf(wt, bfhi(v.x), acc[1]);           \
  acc[2] = fmaf(wt, bflo(v.y), acc[2]);           \
  acc[3] = fmaf(wt, bfhi(v.y), acc[3]);           \
  acc[4] = fmaf(wt, bflo(v.z), acc[4]);           \
  acc[5] = fmaf(wt, bfhi(v.z), acc[5]);           \
  acc[6] = fmaf(wt, bflo(v.w), acc[6]);           \
  acc[7] = fmaf(wt, bfhi(v.w), acc[7]);

template <int MODE>
__global__ __launch_bounds__(256) void agg128_bf16_kernel(
    const unsigned short* __restrict__ h, const int* __restrict__ offs,
    const int2* __restrict__ esw, const float* __restrict__ bias,
    const unsigned short* __restrict__ x1in, unsigned short* __restrict__ out_main,
    unsigned short* __restrict__ out_x1, int n) {
  const int lane = threadIdx.x & 63;
  const int g = lane >> 4;
  const int fl = lane & 15;
  const int node = blockIdx.x * 4 + (threadIdx.x >> 6);
  if (node >= n) return;
  const int s0 = offs[node];
  const int s1 = offs[node + 1];
  float accA[8] = {0.f, 0.f, 0.f, 0.f, 0.f, 0.f, 0.f, 0.f};
  float accB[8] = {0.f, 0.f, 0.f, 0.f, 0.f, 0.f, 0.f, 0.f};
  int e = s0 + g;
  for (; e + 12 < s1; e += 16) {  // 4 edges of this group in flight
    int2 rA = esw[e];
    int2 rB = esw[e + 4];
    int2 rC = esw[e + 8];
    int2 rD = esw[e + 12];
    uint4 vA = *(const uint4*)&h[(size_t)rA.x * 128 + fl * 8];
    uint4 vB = *(const uint4*)&h[(size_t)rB.x * 128 + fl * 8];
    uint4 vC = *(const uint4*)&h[(size_t)rC.x * 128 + fl * 8];
    uint4 vD = *(const uint4*)&h[(size_t)rD.x * 128 + fl * 8];
    float wA = __int_as_float(rA.y);
    float wB = __int_as_float(rB.y);
    float wC = __int_as_float(rC.y);
    float wD = __int_as_float(rD.y);
    ACC8(accA, wA, vA);
    ACC8(accB, wB, vB);
    ACC8(accA, wC, vC);
    ACC8(accB, wD, vD);
  }
  for (; e < s1; e += 4) {
    int2 rA = esw[e];
    float wA = __int_as_float(rA.y);
    uint4 vA = *(const uint4*)&h[(size_t)rA.x * 128 + fl * 8];
    ACC8(accA, wA, vA);
  }
  float acc[8];
#pragma unroll
  for (int i = 0; i < 8; ++i) acc[i] = accA[i] + accB[i];
#pragma unroll
  for (int msk = 16; msk < 64; msk <<= 1)
#pragma unroll
    for (int i = 0; i < 8; ++i) acc[i] += __shfl_xor(acc[i], msk, 64);
  if (g == 0) {
    float4 b0 = *(const float4*)&bias[fl * 8];
    float4 b1 = *(const float4*)&bias[fl * 8 + 4];
    float v[8];
    v[0] = acc[0] + b0.x; v[1] = acc[1] + b0.y; v[2] = acc[2] + b0.z;
    v[3] = acc[3] + b0.w; v[4] = acc[4] + b1.x; v[5] = acc[5] + b1.y;
    v[6] = acc[6] + b1.z; v[7] = acc[7] + b1.w;
    size_t o = (size_t)node * 128 + fl * 8;
    float hn[8];
    if (MODE == 0) {
      uint4 xo;
      xo.x = f2bf2(v[0], v[1]); xo.y = f2bf2(v[2], v[3]);
      xo.z = f2bf2(v[4], v[5]); xo.w = f2bf2(v[6], v[7]);
      *(uint4*)&out_x1[o] = xo;
#pragma unroll
      for (int i = 0; i < 8; ++i) hn[i] = v[i] + relu_f(v[i]);
    } else {
      uint4 x1v = *(const uint4*)&x1in[o];
      float xv[8] = {bflo(x1v.x), bfhi(x1v.x), bflo(x1v.y), bfhi(x1v.y),
                     bflo(x1v.z), bfhi(x1v.z), bflo(x1v.w), bfhi(x1v.w)};
#pragma unroll
      for (int i = 0; i < 8; ++i) hn[i] = xv[i] + relu_f(v[i]);
    }
    uint4 ho;
    ho.x = f2bf2(hn[0], hn[1]); ho.y = f2bf2(hn[2], hn[3]);
    ho.z = f2bf2(hn[4], hn[5]); ho.w = f2bf2(hn[6], hn[7]);
    *(uint4*)&out_main[o] = ho;
  }
}

// ---------------- aggregation, D=64 bf16 rows -> fp32 out, unroll-2 --------
__global__ __launch_bounds__(256) void agg64_bf16_kernel(
    const unsigned short* __restrict__ h, const int* __restrict__ offs,
    const int2* __restrict__ esw, const float* __restrict__ bias,
    float* __restrict__ out, int n) {
  const int lane = threadIdx.x & 63;
  const int g = lane >> 3;
  const int fl = lane & 7;
  const int node = blockIdx.x * 4 + (threadIdx.x >> 6);
  if (node >= n) return;
  const int s0 = offs[node];
  const int s1 = offs[node + 1];
  float accA[8] = {0.f, 0.f, 0.f, 0.f, 0.f, 0.f, 0.f, 0.f};
  float accB[8] = {0.f, 0.f, 0.f, 0.f, 0.f, 0.f, 0.f, 0.f};
  int e = s0 + g;
  for (; e + 8 < s1; e += 16) {
    int2 rA = esw[e];
    int2 rB = esw[e + 8];
    uint4 vA = *(const uint4*)&h[(size_t)rA.x * 64 + fl * 8];
    uint4 vB = *(const uint4*)&h[(size_t)rB.x * 64 + fl * 8];
    float wA = __int_as_float(rA.y);
    float wB = __int_as_float(rB.y);
    ACC8(accA, wA, vA);
    ACC8(accB, wB, vB);
  }
  if (e < s1) {
    int2 rA = esw[e];
    float wA = __int_as_float(rA.y);
    uint4 vA = *(const uint4*)&h[(size_t)rA.x * 64 + fl * 8];
    ACC8(accA, wA, vA);
  }
  float acc[8];
#pragma unroll
  for (int i = 0; i < 8; ++i) acc[i] = accA[i] + accB[i];
#pragma unroll
  for (int msk = 8; msk < 64; msk <<= 1)
#pragma unroll
    for (int i = 0; i < 8; ++i) acc[i] += __shfl_xor(acc[i], msk, 64);
  if (g == 0) {
    float4 b0 = *(const float4*)&bias[fl * 8];
    float4 b1 = *(const float4*)&bias[fl * 8 + 4];
    float4 o0, o1;
    o0.x = acc[0] + b0.x; o0.y = acc[1] + b0.y;
    o0.z = acc[2] + b0.z; o0.w = acc[3] + b0.w;
    o1.x = acc[4] + b1.x; o1.y = acc[5] + b1.y;
    o1.z = acc[6] + b1.z; o1.w = acc[7] + b1.w;
    size_t o = (size_t)node * 64 + fl * 8;
    *(float4*)&out[o] = o0;
    *(float4*)&out[o + 4] = o1;
  }
}

extern "C" void kernel_launch(void* const* d_in, const int* in_sizes, int n_in,
                              void* d_out, int out_size, void* d_ws, size_t ws_size,
                              hipStream_t stream) {
  const float* x  = (const float*)d_in[0];
  const int*   ei = (const int*)d_in[1];
  const float* ew = (const float*)d_in[2];
  const float* W1 = (const float*)d_in[3];
  const float* b1 = (const float*)d_in[4];
  const float* W2 = (const float*)d_in[5];
  const float* b2 = (const float*)d_in[6];
  const float* W3 = (const float*)d_in[7];
  const float* b3 = (const float*)d_in[8];
  const int N = in_sizes[0] / 128;   // 50000
  const int E = in_sizes[2];         // 800000
  const int* src = ei;
  const int* dst = ei + E;
  const int nb = (N + 255) >> BSHIFT;  // 196

  char* p = (char*)d_ws;
  auto alloc = [&](size_t bytes) {
    void* q = (void*)p;
    p += (bytes + 511) & ~(size_t)511;
    return q;
  };
  int*   offs   = (int*)alloc((size_t)(N + 1) * 4);
  int*   bcount = (int*)alloc(MAXB * 4);
  int*   bstart = (int*)alloc((MAXB + 1) * 4);
  int*   bcur   = (int*)alloc(MAXB * 4);
  int2*  tmp    = (int2*)alloc((size_t)E * 8);
  int2*  esw    = (int2*)alloc((size_t)E * 8);
  unsigned short* hb  = (unsigned short*)alloc((size_t)N * 128 * 2);
  unsigned short* x1b = (unsigned short*)alloc((size_t)N * 128 * 2);
  unsigned short* cb  = (unsigned short*)alloc((size_t)N * 128 * 2);
  unsigned short* P1  = (unsigned short*)alloc(16384 * 2);
  unsigned short* P2  = (unsigned short*)alloc(16384 * 2);
  unsigned short* P3  = (unsigned short*)alloc(8192 * 2);
  (void)ws_size; (void)n_in; (void)out_size;

  const int mmGrid = (N + 63) / 64;            // 782
  const int aggGrid = (N + 3) / 4;
  const int binBlocks = (E + TILE - 1) / TILE; // 196

  hipMemsetAsync(bcount, 0, MAXB * 4, stream);
  count_pack_kernel<<<256 + 160, 256, 0, stream>>>(dst, bcount, E, nb,
                                                   W1, W2, W3, P1, P2, P3);
  bucket_scan_kernel<<<1, 256, 0, stream>>>(bcount, bstart, bcur, offs, N, E, nb);
  bin_mm1_kernel<<<binBlocks + mmGrid, 256, 40960, stream>>>(
      src, dst, ew, bcur, tmp, E, nb, binBlocks, x, P1, hb, N);
  csr_kernel<<<nb, 256, 0, stream>>>(tmp, bstart, offs, esw, N);

  // Layer 1 aggregation (mm1 done inside bin_mm1)
  agg128_bf16_kernel<0><<<aggGrid, 256, 0, stream>>>(hb, offs, esw, b1,
                                                     nullptr, cb, x1b, N);
  // Layer 2
  mm_mfma_kernel<128, false><<<mmGrid, 256, 17408, stream>>>(cb, P2, hb, N);
  agg128_bf16_kernel<1><<<aggGrid, 256, 0, stream>>>(hb, offs, esw, b2,
                                                     x1b, cb, nullptr, N);
  // Layer 3
  mm_mfma_kernel<64, false><<<mmGrid, 256, 17408, stream>>>(cb, P3, hb, N);
  agg64_bf16_kernel<<<aggGrid, 256, 0, stream>>>(hb, offs, esw, b3,
                                                 (float*)d_out, N);
}